// Round 3
// baseline (594.155 us; speedup 1.0000x reference)
//
#include <hip/hip_runtime.h>

#define N_NODES 100000
#define N_EDGES 1600000
#define IN_CH   165
#define SCAN_CHUNK 2048   // 256 threads * 8 elems
#define NB_SCAN ((N_NODES + SCAN_CHUNK - 1) / SCAN_CHUNK)

// ---------------- degree / norm ----------------
__global__ void count_kernel(const int* __restrict__ col, int* __restrict__ cnt, int E) {
    int i = blockIdx.x * blockDim.x + threadIdx.x;
    int stride = gridDim.x * blockDim.x;
    for (int e = i; e < E; e += stride) atomicAdd(&cnt[col[e]], 1);
}

__global__ void dis_kernel(const int* __restrict__ cnt, float* __restrict__ dis, int n) {
    int i = blockIdx.x * blockDim.x + threadIdx.x;
    if (i < n) dis[i] = rsqrtf((float)(cnt[i] + 1));   // +1 = self loop
}

// ---------------- exclusive scan (3 kernels) ----------------
__global__ void scan1_kernel(const int* __restrict__ cnt, int* __restrict__ off,
                             int* __restrict__ bsum, int n) {
    __shared__ int sh[256];
    int t = threadIdx.x;
    int base = blockIdx.x * SCAN_CHUNK + t * 8;
    int v[8];
    int run = 0;
    #pragma unroll
    for (int j = 0; j < 8; ++j) {
        int c = (base + j < n) ? cnt[base + j] : 0;
        v[j] = run; run += c;
    }
    sh[t] = run;
    __syncthreads();
    for (int o = 1; o < 256; o <<= 1) {
        int x = (t >= o) ? sh[t - o] : 0;
        __syncthreads();
        sh[t] += x;
        __syncthreads();
    }
    int prev = (t > 0) ? sh[t - 1] : 0;
    #pragma unroll
    for (int j = 0; j < 8; ++j)
        if (base + j < n) off[base + j] = prev + v[j];
    if (t == 255) bsum[blockIdx.x] = sh[255];
}

// single-wave shuffle scan (NB_SCAN=49 <= 64)
__global__ void scan2_kernel(int* bsum, int nb) {
    int lane = threadIdx.x;
    int orig = (lane < nb) ? bsum[lane] : 0;
    int v = orig;
    #pragma unroll
    for (int o = 1; o < 64; o <<= 1) {
        int t = __shfl_up(v, o);
        if (lane >= o) v += t;
    }
    if (lane < nb) bsum[lane] = v - orig;   // exclusive
}

__global__ void scan3_kernel(int* __restrict__ off, const int* __restrict__ bsum,
                             int* __restrict__ cur, int n, int E) {
    int i = blockIdx.x * blockDim.x + threadIdx.x;
    if (i < n) {
        int o = off[i] + bsum[i / SCAN_CHUNK];
        off[i] = o;
        cur[i] = o;
    } else if (i == n) {
        off[n] = E;
    }
}

// ---------------- CSR scatter ----------------
__global__ void scatter_kernel(const int* __restrict__ row, const int* __restrict__ col,
                               int* __restrict__ cur, int* __restrict__ srt, int E) {
    int i = blockIdx.x * blockDim.x + threadIdx.x;
    int stride = gridDim.x * blockDim.x;
    for (int e = i; e < E; e += stride) {
        int c = col[e];
        int p = atomicAdd(&cur[c], 1);
        srt[p] = row[e];
    }
}

// ---------------- dense GEMM: M[n][NOUT] = dis[n] * (X[n][KTOT] @ W[KTOT][NOUT]) ----
// 8 nodes x 8 channels per thread, all-b128 LDS reads, 4-k chunks.
// Nodes strided by TY; XPAD chosen so ty*XPAD%32 spreads bank quads (and rows stay
// 16B-aligned). Channels: two float4 at tx*4 and NOUT/2+tx*4.
template<int NOUT, int KTOT, int KC, int TX, int XPAD>
__launch_bounds__(256, 3)
__global__ void gemm_kernel(const float* __restrict__ X, const float* __restrict__ W,
                            const float* __restrict__ dis, float* __restrict__ M,
                            int n_nodes) {
    constexpr int TY = 256 / TX;
    constexpr int RN = 8;
    constexpr int NT = TY * RN;
    constexpr int WPAD = NOUT + 4;
    __shared__ float xs[NT][XPAD];
    __shared__ float ws[KC][WPAD];
    int t = threadIdx.x;
    int tx = t % TX, ty = t / TX;
    long node0 = (long)blockIdx.x * NT;

    float acc[RN][8];
    #pragma unroll
    for (int i = 0; i < RN; ++i)
        #pragma unroll
        for (int j = 0; j < 8; ++j) acc[i][j] = 0.f;

    for (int k0 = 0; k0 < KTOT; k0 += KC) {
        for (int i = t; i < NT * KC; i += 256) {
            int n = i / KC, k = i - n * KC;
            long node = node0 + n;
            int kk = k0 + k;
            xs[n][k] = (node < n_nodes && kk < KTOT) ? X[node * KTOT + kk] : 0.f;
        }
        for (int i = t; i < KC * NOUT; i += 256) {
            int k = i / NOUT, c = i - k * NOUT;
            int kk = k0 + k;
            ws[k][c] = (kk < KTOT) ? W[(size_t)kk * NOUT + c] : 0.f;
        }
        __syncthreads();
        #pragma unroll 1
        for (int k = 0; k < KC; k += 4) {
            float4 a[RN];
            #pragma unroll
            for (int i = 0; i < RN; ++i)
                a[i] = *(const float4*)&xs[ty + i * TY][k];
            #pragma unroll
            for (int kk = 0; kk < 4; ++kk) {
                float4 b0 = *(const float4*)&ws[k + kk][tx * 4];
                float4 b1 = *(const float4*)&ws[k + kk][NOUT / 2 + tx * 4];
                #pragma unroll
                for (int i = 0; i < RN; ++i) {
                    float av = (kk == 0) ? a[i].x : (kk == 1) ? a[i].y
                             : (kk == 2) ? a[i].z : a[i].w;
                    acc[i][0] = fmaf(av, b0.x, acc[i][0]);
                    acc[i][1] = fmaf(av, b0.y, acc[i][1]);
                    acc[i][2] = fmaf(av, b0.z, acc[i][2]);
                    acc[i][3] = fmaf(av, b0.w, acc[i][3]);
                    acc[i][4] = fmaf(av, b1.x, acc[i][4]);
                    acc[i][5] = fmaf(av, b1.y, acc[i][5]);
                    acc[i][6] = fmaf(av, b1.z, acc[i][6]);
                    acc[i][7] = fmaf(av, b1.w, acc[i][7]);
                }
            }
        }
        __syncthreads();
    }
    #pragma unroll
    for (int i = 0; i < RN; ++i) {
        long node = node0 + ty + i * TY;
        if (node < n_nodes) {
            float d = dis[node];
            *(float4*)&M[node * NOUT + tx * 4] =
                make_float4(acc[i][0] * d, acc[i][1] * d, acc[i][2] * d, acc[i][3] * d);
            *(float4*)&M[node * NOUT + NOUT / 2 + tx * 4] =
                make_float4(acc[i][4] * d, acc[i][5] * d, acc[i][6] * d, acc[i][7] * d);
        }
    }
}

// ---------------- aggregation layer 1: 128 ch, wave-per-node ----------------
// ms is pre-scaled by dis[src]; out = relu(dn * (ms[n] + sum ms[src]) + b1)
__global__ void agg1_kernel(const float* __restrict__ ms, const int* __restrict__ srt,
                            const int* __restrict__ off, const float* __restrict__ dis,
                            const float* __restrict__ b1, float* __restrict__ h1) {
    int wave = threadIdx.x >> 6;
    int lane = threadIdx.x & 63;
    int n = blockIdx.x * 4 + wave;
    if (n >= N_NODES) return;
    float dn = dis[n];
    float2 a = ((const float2*)(ms + (size_t)n * 128))[lane];
    float accx = a.x, accy = a.y;
    int s0 = off[n], s1 = off[n + 1];
    for (int base = s0; base < s1; base += 64) {
        int sv = (base + lane < s1) ? srt[base + lane] : 0;
        int cnt = min(64, s1 - base);
        int j = 0;
        for (; j + 7 < cnt; j += 8) {
            float2 v0 = ((const float2*)(ms + (size_t)__builtin_amdgcn_readlane(sv, j + 0) * 128))[lane];
            float2 v1 = ((const float2*)(ms + (size_t)__builtin_amdgcn_readlane(sv, j + 1) * 128))[lane];
            float2 v2 = ((const float2*)(ms + (size_t)__builtin_amdgcn_readlane(sv, j + 2) * 128))[lane];
            float2 v3 = ((const float2*)(ms + (size_t)__builtin_amdgcn_readlane(sv, j + 3) * 128))[lane];
            float2 v4 = ((const float2*)(ms + (size_t)__builtin_amdgcn_readlane(sv, j + 4) * 128))[lane];
            float2 v5 = ((const float2*)(ms + (size_t)__builtin_amdgcn_readlane(sv, j + 5) * 128))[lane];
            float2 v6 = ((const float2*)(ms + (size_t)__builtin_amdgcn_readlane(sv, j + 6) * 128))[lane];
            float2 v7 = ((const float2*)(ms + (size_t)__builtin_amdgcn_readlane(sv, j + 7) * 128))[lane];
            accx += v0.x + v1.x + v2.x + v3.x + v4.x + v5.x + v6.x + v7.x;
            accy += v0.y + v1.y + v2.y + v3.y + v4.y + v5.y + v6.y + v7.y;
        }
        for (; j < cnt; ++j) {
            int s = __builtin_amdgcn_readlane(sv, j);
            float2 v = ((const float2*)(ms + (size_t)s * 128))[lane];
            accx += v.x; accy += v.y;
        }
    }
    float2 b = ((const float2*)b1)[lane];
    float rx = fmaxf(accx * dn + b.x, 0.f);
    float ry = fmaxf(accy * dn + b.y, 0.f);
    ((float2*)(h1 + (size_t)n * 128))[lane] = make_float2(rx, ry);
}

// ---------------- aggregation layer 2 (64 ch) + output GEMM (64 -> 2) ----------------
__global__ void agg2_kernel(const float* __restrict__ ms, const int* __restrict__ srt,
                            const int* __restrict__ off, const float* __restrict__ dis,
                            const float* __restrict__ b2, const float* __restrict__ Wo,
                            const float* __restrict__ bo, float* __restrict__ out) {
    int wave = threadIdx.x >> 6;
    int lane = threadIdx.x & 63;
    int n = blockIdx.x * 4 + wave;
    if (n >= N_NODES) return;
    float dn = dis[n];
    float acc = ms[(size_t)n * 64 + lane];
    int s0 = off[n], s1 = off[n + 1];
    for (int base = s0; base < s1; base += 64) {
        int sv = (base + lane < s1) ? srt[base + lane] : 0;
        int cnt = min(64, s1 - base);
        int j = 0;
        for (; j + 7 < cnt; j += 8) {
            float v0 = ms[(size_t)__builtin_amdgcn_readlane(sv, j + 0) * 64 + lane];
            float v1 = ms[(size_t)__builtin_amdgcn_readlane(sv, j + 1) * 64 + lane];
            float v2 = ms[(size_t)__builtin_amdgcn_readlane(sv, j + 2) * 64 + lane];
            float v3 = ms[(size_t)__builtin_amdgcn_readlane(sv, j + 3) * 64 + lane];
            float v4 = ms[(size_t)__builtin_amdgcn_readlane(sv, j + 4) * 64 + lane];
            float v5 = ms[(size_t)__builtin_amdgcn_readlane(sv, j + 5) * 64 + lane];
            float v6 = ms[(size_t)__builtin_amdgcn_readlane(sv, j + 6) * 64 + lane];
            float v7 = ms[(size_t)__builtin_amdgcn_readlane(sv, j + 7) * 64 + lane];
            acc += v0 + v1 + v2 + v3 + v4 + v5 + v6 + v7;
        }
        for (; j < cnt; ++j) {
            acc += ms[(size_t)__builtin_amdgcn_readlane(sv, j) * 64 + lane];
        }
    }
    float v = fmaxf(acc * dn + b2[lane], 0.f);
    float p0 = v * Wo[lane * 2];
    float p1 = v * Wo[lane * 2 + 1];
    #pragma unroll
    for (int o = 32; o > 0; o >>= 1) {
        p0 += __shfl_xor(p0, o);
        p1 += __shfl_xor(p1, o);
    }
    if (lane == 0) {
        out[(size_t)n * 2]     = p0 + bo[0];
        out[(size_t)n * 2 + 1] = p1 + bo[1];
    }
}

// ---------------- launch ----------------
extern "C" void kernel_launch(void* const* d_in, const int* in_sizes, int n_in,
                              void* d_out, int out_size, void* d_ws, size_t ws_size,
                              hipStream_t stream) {
    const float* x  = (const float*)d_in[0];
    const int*   ei = (const int*)d_in[1];
    const int*   row = ei;
    const int*   col = ei + N_EDGES;
    const float* W1 = (const float*)d_in[2];
    const float* b1 = (const float*)d_in[3];
    const float* W2 = (const float*)d_in[4];
    const float* b2 = (const float*)d_in[5];
    const float* Wo = (const float*)d_in[6];
    const float* bo = (const float*)d_in[7];
    float* out = (float*)d_out;

    char* base = (char*)d_ws;
    auto alloc = [&](size_t bytes) {
        char* p = base;
        base += (bytes + 255) & ~(size_t)255;
        return p;
    };
    int*   cnt  = (int*)alloc((size_t)N_NODES * 4);
    int*   off  = (int*)alloc((size_t)(N_NODES + 1) * 4);
    int*   cur  = (int*)alloc((size_t)N_NODES * 4);
    float* dis  = (float*)alloc((size_t)N_NODES * 4);
    int*   bsum = (int*)alloc(256);
    int*   srt  = (int*)alloc((size_t)N_EDGES * 4);
    float* m    = (float*)alloc((size_t)N_NODES * 128 * 4);   // m1, reused as m2
    float* h1   = (float*)alloc((size_t)N_NODES * 128 * 4);

    hipMemsetAsync(cnt, 0, (size_t)N_NODES * 4, stream);
    count_kernel<<<1024, 256, 0, stream>>>(col, cnt, N_EDGES);
    dis_kernel<<<(N_NODES + 255) / 256, 256, 0, stream>>>(cnt, dis, N_NODES);
    scan1_kernel<<<NB_SCAN, 256, 0, stream>>>(cnt, off, bsum, N_NODES);
    scan2_kernel<<<1, 64, 0, stream>>>(bsum, NB_SCAN);
    scan3_kernel<<<(N_NODES + 256) / 256, 256, 0, stream>>>(off, bsum, cur, N_NODES, N_EDGES);
    scatter_kernel<<<1024, 256, 0, stream>>>(row, col, cur, srt, N_EDGES);

    // layer 1: m = dis * (x @ W1); 128 nodes/block, KC=44 (4 zero-padded tiles)
    gemm_kernel<128, 165, 44, 16, 52><<<(N_NODES + 127) / 128, 256, 0, stream>>>(x, W1, dis, m, N_NODES);
    agg1_kernel<<<(N_NODES + 3) / 4, 256, 0, stream>>>(m, srt, off, dis, b1, h1);

    // layer 2: m = dis * (h1 @ W2); 256 nodes/block, KC=32 (4 exact tiles)
    gemm_kernel<64, 128, 32, 8, 36><<<(N_NODES + 255) / 256, 256, 0, stream>>>(h1, W2, dis, m, N_NODES);
    agg2_kernel<<<(N_NODES + 3) / 4, 256, 0, stream>>>(m, srt, off, dis, b2, Wo, bo, out);
}

// Round 4
// 584.799 us; speedup vs baseline: 1.0160x; 1.0160x over previous
//
#include <hip/hip_runtime.h>

#define N_NODES 100000
#define N_EDGES 1600000
#define IN_CH   165
#define SCAN_CHUNK 2048   // 256 threads * 8 elems
#define NB_SCAN ((N_NODES + SCAN_CHUNK - 1) / SCAN_CHUNK)

// ---------------- degree / norm ----------------
__global__ void count_kernel(const int* __restrict__ col, int* __restrict__ cnt, int E) {
    int i = blockIdx.x * blockDim.x + threadIdx.x;
    int stride = gridDim.x * blockDim.x;
    for (int e = i; e < E; e += stride) atomicAdd(&cnt[col[e]], 1);
}

__global__ void dis_kernel(const int* __restrict__ cnt, float* __restrict__ dis, int n) {
    int i = blockIdx.x * blockDim.x + threadIdx.x;
    if (i < n) dis[i] = rsqrtf((float)(cnt[i] + 1));   // +1 = self loop
}

// ---------------- exclusive scan (3 kernels) ----------------
__global__ void scan1_kernel(const int* __restrict__ cnt, int* __restrict__ off,
                             int* __restrict__ bsum, int n) {
    __shared__ int sh[256];
    int t = threadIdx.x;
    int base = blockIdx.x * SCAN_CHUNK + t * 8;
    int v[8];
    int run = 0;
    #pragma unroll
    for (int j = 0; j < 8; ++j) {
        int c = (base + j < n) ? cnt[base + j] : 0;
        v[j] = run; run += c;
    }
    sh[t] = run;
    __syncthreads();
    for (int o = 1; o < 256; o <<= 1) {
        int x = (t >= o) ? sh[t - o] : 0;
        __syncthreads();
        sh[t] += x;
        __syncthreads();
    }
    int prev = (t > 0) ? sh[t - 1] : 0;
    #pragma unroll
    for (int j = 0; j < 8; ++j)
        if (base + j < n) off[base + j] = prev + v[j];
    if (t == 255) bsum[blockIdx.x] = sh[255];
}

// single-wave shuffle scan (NB_SCAN=49 <= 64)
__global__ void scan2_kernel(int* bsum, int nb) {
    int lane = threadIdx.x;
    int orig = (lane < nb) ? bsum[lane] : 0;
    int v = orig;
    #pragma unroll
    for (int o = 1; o < 64; o <<= 1) {
        int t = __shfl_up(v, o);
        if (lane >= o) v += t;
    }
    if (lane < nb) bsum[lane] = v - orig;   // exclusive
}

__global__ void scan3_kernel(int* __restrict__ off, const int* __restrict__ bsum,
                             int* __restrict__ cur, int n, int E) {
    int i = blockIdx.x * blockDim.x + threadIdx.x;
    if (i < n) {
        int o = off[i] + bsum[i / SCAN_CHUNK];
        off[i] = o;
        cur[i] = o;
    } else if (i == n) {
        off[n] = E;
    }
}

// ---------------- CSR scatter ----------------
__global__ void scatter_kernel(const int* __restrict__ row, const int* __restrict__ col,
                               int* __restrict__ cur, int* __restrict__ srt, int E) {
    int i = blockIdx.x * blockDim.x + threadIdx.x;
    int stride = gridDim.x * blockDim.x;
    for (int e = i; e < E; e += stride) {
        int c = col[e];
        int p = atomicAdd(&cur[c], 1);
        srt[p] = row[e];
    }
}

// ---------------- dense GEMM: M[n][NOUT] = dis[n] * (X[n][KTOT] @ W[KTOT][NOUT]) ----
// Transposed X tile xs[k][node]: one b128 = 4 nodes (16-wide lane broadcast).
// Per k: 3 ds_read_b128 + 32 FMA (8 nodes x 4 ch outer product), 1-deep pipeline.
template<int NOUT, int KTOT, int KC, int TX>
__launch_bounds__(256, 4)
__global__ void gemm_kernel(const float* __restrict__ X, const float* __restrict__ W,
                            const float* __restrict__ dis, float* __restrict__ M,
                            int n_nodes) {
    constexpr int TY = 256 / TX;
    constexpr int RN = 8;
    constexpr int NT = TY * RN;      // nodes per block
    constexpr int NTP = NT + 1;
    constexpr int WROW = NOUT + 4;
    __shared__ float xs[KC][NTP];
    __shared__ float ws[KC][WROW];
    int t = threadIdx.x;
    int tx = t % TX, ty = t / TX;
    int nb = ty * RN;
    long node0 = (long)blockIdx.x * NT;

    float acc[RN][4];
    #pragma unroll
    for (int i = 0; i < RN; ++i)
        #pragma unroll
        for (int j = 0; j < 4; ++j) acc[i][j] = 0.f;

    auto fma32 = [&](float4 a0, float4 a1, float4 b) {
        float av[RN] = {a0.x, a0.y, a0.z, a0.w, a1.x, a1.y, a1.z, a1.w};
        #pragma unroll
        for (int i = 0; i < RN; ++i) {
            acc[i][0] = fmaf(av[i], b.x, acc[i][0]);
            acc[i][1] = fmaf(av[i], b.y, acc[i][1]);
            acc[i][2] = fmaf(av[i], b.z, acc[i][2]);
            acc[i][3] = fmaf(av[i], b.w, acc[i][3]);
        }
    };

    for (int k0 = 0; k0 < KTOT; k0 += KC) {
        // stage X tile transposed: xs[kk][node]
        for (int idx = t; idx < NT * KC; idx += 256) {
            int node = idx / KC, kk = idx - node * KC;
            int k = k0 + kk;
            long g = node0 + node;
            xs[kk][node] = (g < n_nodes && k < KTOT) ? X[g * KTOT + k] : 0.f;
        }
        // stage W tile: ws[kk][c]
        for (int idx = t; idx < KC * NOUT; idx += 256) {
            int kk = idx / NOUT, c = idx - kk * NOUT;
            int k = k0 + kk;
            ws[kk][c] = (k < KTOT) ? W[(size_t)k * NOUT + c] : 0.f;
        }
        __syncthreads();

        float4 a0 = *(const float4*)&xs[0][nb];
        float4 a1 = *(const float4*)&xs[0][nb + 4];
        float4 b  = *(const float4*)&ws[0][tx * 4];
        for (int k = 0; k < KC - 1; ++k) {
            float4 a0n = *(const float4*)&xs[k + 1][nb];
            float4 a1n = *(const float4*)&xs[k + 1][nb + 4];
            float4 bn  = *(const float4*)&ws[k + 1][tx * 4];
            fma32(a0, a1, b);
            a0 = a0n; a1 = a1n; b = bn;
        }
        fma32(a0, a1, b);
        __syncthreads();
    }

    #pragma unroll
    for (int i = 0; i < RN; ++i) {
        long node = node0 + nb + i;
        if (node < n_nodes) {
            float d = dis[node];
            *(float4*)&M[node * NOUT + tx * 4] =
                make_float4(acc[i][0] * d, acc[i][1] * d, acc[i][2] * d, acc[i][3] * d);
        }
    }
}

// ---------------- aggregation layer 1: 128 ch, wave-per-node ----------------
// ms is pre-scaled by dis[src]; out = relu(dn * (ms[n] + sum ms[src]) + b1)
__global__ void agg1_kernel(const float* __restrict__ ms, const int* __restrict__ srt,
                            const int* __restrict__ off, const float* __restrict__ dis,
                            const float* __restrict__ b1, float* __restrict__ h1) {
    int wave = threadIdx.x >> 6;
    int lane = threadIdx.x & 63;
    int n = blockIdx.x * 4 + wave;
    if (n >= N_NODES) return;
    float dn = dis[n];
    float2 a = ((const float2*)(ms + (size_t)n * 128))[lane];
    float accx = a.x, accy = a.y;
    int s0 = off[n], s1 = off[n + 1];
    for (int base = s0; base < s1; base += 64) {
        int sv = (base + lane < s1) ? srt[base + lane] : 0;
        int cnt = min(64, s1 - base);
        int j = 0;
        for (; j + 7 < cnt; j += 8) {
            float2 v0 = ((const float2*)(ms + (size_t)__builtin_amdgcn_readlane(sv, j + 0) * 128))[lane];
            float2 v1 = ((const float2*)(ms + (size_t)__builtin_amdgcn_readlane(sv, j + 1) * 128))[lane];
            float2 v2 = ((const float2*)(ms + (size_t)__builtin_amdgcn_readlane(sv, j + 2) * 128))[lane];
            float2 v3 = ((const float2*)(ms + (size_t)__builtin_amdgcn_readlane(sv, j + 3) * 128))[lane];
            float2 v4 = ((const float2*)(ms + (size_t)__builtin_amdgcn_readlane(sv, j + 4) * 128))[lane];
            float2 v5 = ((const float2*)(ms + (size_t)__builtin_amdgcn_readlane(sv, j + 5) * 128))[lane];
            float2 v6 = ((const float2*)(ms + (size_t)__builtin_amdgcn_readlane(sv, j + 6) * 128))[lane];
            float2 v7 = ((const float2*)(ms + (size_t)__builtin_amdgcn_readlane(sv, j + 7) * 128))[lane];
            accx += v0.x + v1.x + v2.x + v3.x + v4.x + v5.x + v6.x + v7.x;
            accy += v0.y + v1.y + v2.y + v3.y + v4.y + v5.y + v6.y + v7.y;
        }
        for (; j < cnt; ++j) {
            int s = __builtin_amdgcn_readlane(sv, j);
            float2 v = ((const float2*)(ms + (size_t)s * 128))[lane];
            accx += v.x; accy += v.y;
        }
    }
    float2 b = ((const float2*)b1)[lane];
    float rx = fmaxf(accx * dn + b.x, 0.f);
    float ry = fmaxf(accy * dn + b.y, 0.f);
    ((float2*)(h1 + (size_t)n * 128))[lane] = make_float2(rx, ry);
}

// ---------------- aggregation layer 2 (64 ch) + output GEMM (64 -> 2) ----------------
__global__ void agg2_kernel(const float* __restrict__ ms, const int* __restrict__ srt,
                            const int* __restrict__ off, const float* __restrict__ dis,
                            const float* __restrict__ b2, const float* __restrict__ Wo,
                            const float* __restrict__ bo, float* __restrict__ out) {
    int wave = threadIdx.x >> 6;
    int lane = threadIdx.x & 63;
    int n = blockIdx.x * 4 + wave;
    if (n >= N_NODES) return;
    float dn = dis[n];
    float acc = ms[(size_t)n * 64 + lane];
    int s0 = off[n], s1 = off[n + 1];
    for (int base = s0; base < s1; base += 64) {
        int sv = (base + lane < s1) ? srt[base + lane] : 0;
        int cnt = min(64, s1 - base);
        int j = 0;
        for (; j + 7 < cnt; j += 8) {
            float v0 = ms[(size_t)__builtin_amdgcn_readlane(sv, j + 0) * 64 + lane];
            float v1 = ms[(size_t)__builtin_amdgcn_readlane(sv, j + 1) * 64 + lane];
            float v2 = ms[(size_t)__builtin_amdgcn_readlane(sv, j + 2) * 64 + lane];
            float v3 = ms[(size_t)__builtin_amdgcn_readlane(sv, j + 3) * 64 + lane];
            float v4 = ms[(size_t)__builtin_amdgcn_readlane(sv, j + 4) * 64 + lane];
            float v5 = ms[(size_t)__builtin_amdgcn_readlane(sv, j + 5) * 64 + lane];
            float v6 = ms[(size_t)__builtin_amdgcn_readlane(sv, j + 6) * 64 + lane];
            float v7 = ms[(size_t)__builtin_amdgcn_readlane(sv, j + 7) * 64 + lane];
            acc += v0 + v1 + v2 + v3 + v4 + v5 + v6 + v7;
        }
        for (; j < cnt; ++j) {
            acc += ms[(size_t)__builtin_amdgcn_readlane(sv, j) * 64 + lane];
        }
    }
    float v = fmaxf(acc * dn + b2[lane], 0.f);
    float p0 = v * Wo[lane * 2];
    float p1 = v * Wo[lane * 2 + 1];
    #pragma unroll
    for (int o = 32; o > 0; o >>= 1) {
        p0 += __shfl_xor(p0, o);
        p1 += __shfl_xor(p1, o);
    }
    if (lane == 0) {
        out[(size_t)n * 2]     = p0 + bo[0];
        out[(size_t)n * 2 + 1] = p1 + bo[1];
    }
}

// ---------------- launch ----------------
extern "C" void kernel_launch(void* const* d_in, const int* in_sizes, int n_in,
                              void* d_out, int out_size, void* d_ws, size_t ws_size,
                              hipStream_t stream) {
    const float* x  = (const float*)d_in[0];
    const int*   ei = (const int*)d_in[1];
    const int*   row = ei;
    const int*   col = ei + N_EDGES;
    const float* W1 = (const float*)d_in[2];
    const float* b1 = (const float*)d_in[3];
    const float* W2 = (const float*)d_in[4];
    const float* b2 = (const float*)d_in[5];
    const float* Wo = (const float*)d_in[6];
    const float* bo = (const float*)d_in[7];
    float* out = (float*)d_out;

    char* base = (char*)d_ws;
    auto alloc = [&](size_t bytes) {
        char* p = base;
        base += (bytes + 255) & ~(size_t)255;
        return p;
    };
    int*   cnt  = (int*)alloc((size_t)N_NODES * 4);
    int*   off  = (int*)alloc((size_t)(N_NODES + 1) * 4);
    int*   cur  = (int*)alloc((size_t)N_NODES * 4);
    float* dis  = (float*)alloc((size_t)N_NODES * 4);
    int*   bsum = (int*)alloc(256);
    int*   srt  = (int*)alloc((size_t)N_EDGES * 4);
    float* m    = (float*)alloc((size_t)N_NODES * 128 * 4);   // m1, reused as m2
    float* h1   = (float*)alloc((size_t)N_NODES * 128 * 4);

    hipMemsetAsync(cnt, 0, (size_t)N_NODES * 4, stream);
    count_kernel<<<1024, 256, 0, stream>>>(col, cnt, N_EDGES);
    dis_kernel<<<(N_NODES + 255) / 256, 256, 0, stream>>>(cnt, dis, N_NODES);
    scan1_kernel<<<NB_SCAN, 256, 0, stream>>>(cnt, off, bsum, N_NODES);
    scan2_kernel<<<1, 64, 0, stream>>>(bsum, NB_SCAN);
    scan3_kernel<<<(N_NODES + 256) / 256, 256, 0, stream>>>(off, bsum, cur, N_NODES, N_EDGES);
    scatter_kernel<<<1024, 256, 0, stream>>>(row, col, cur, srt, N_EDGES);

    // layer 1: m = dis * (x @ W1); NT=64 nodes/block, KC=56 (3 zero-padded tiles)
    gemm_kernel<128, 165, 56, 32><<<(N_NODES + 63) / 64, 256, 0, stream>>>(x, W1, dis, m, N_NODES);
    agg1_kernel<<<(N_NODES + 3) / 4, 256, 0, stream>>>(m, srt, off, dis, b1, h1);

    // layer 2: m = dis * (h1 @ W2); NT=128 nodes/block, KC=32 (4 exact tiles)
    gemm_kernel<64, 128, 32, 16><<<(N_NODES + 127) / 128, 256, 0, stream>>>(h1, W2, dis, m, N_NODES);
    agg2_kernel<<<(N_NODES + 3) / 4, 256, 0, stream>>>(m, srt, off, dis, b2, Wo, bo, out);
}

// Round 5
// 478.867 us; speedup vs baseline: 1.2408x; 1.2212x over previous
//
#include <hip/hip_runtime.h>

#define N_NODES 100000
#define N_EDGES 1600000
#define IN_CH   165
#define SCAN_CHUNK 2048   // 256 threads * 8 elems
#define NB_SCAN ((N_NODES + SCAN_CHUNK - 1) / SCAN_CHUNK)

typedef unsigned short ushort_t;
typedef short bfrag8 __attribute__((ext_vector_type(8)));   // 8 bf16 (4 VGPRs)
typedef float f32x4 __attribute__((ext_vector_type(4)));

// bf16 round-to-nearest-even
__device__ __forceinline__ ushort_t f2bf(float f) {
    unsigned u = __float_as_uint(f);
    unsigned r = (u + 0x7fffu + ((u >> 16) & 1u)) >> 16;
    return (ushort_t)r;
}
__device__ __forceinline__ float bf2f(ushort_t h) {
    return __uint_as_float(((unsigned)h) << 16);
}

// ---------------- degree / norm ----------------
__global__ void count_kernel(const int* __restrict__ col, int* __restrict__ cnt, int E) {
    int i = blockIdx.x * blockDim.x + threadIdx.x;
    int stride = gridDim.x * blockDim.x;
    for (int e = i; e < E; e += stride) atomicAdd(&cnt[col[e]], 1);
}

__global__ void dis_kernel(const int* __restrict__ cnt, float* __restrict__ dis, int n) {
    int i = blockIdx.x * blockDim.x + threadIdx.x;
    if (i < n) dis[i] = rsqrtf((float)(cnt[i] + 1));   // +1 = self loop
}

// ---------------- exclusive scan (3 kernels) ----------------
__global__ void scan1_kernel(const int* __restrict__ cnt, int* __restrict__ off,
                             int* __restrict__ bsum, int n) {
    __shared__ int sh[256];
    int t = threadIdx.x;
    int base = blockIdx.x * SCAN_CHUNK + t * 8;
    int v[8];
    int run = 0;
    #pragma unroll
    for (int j = 0; j < 8; ++j) {
        int c = (base + j < n) ? cnt[base + j] : 0;
        v[j] = run; run += c;
    }
    sh[t] = run;
    __syncthreads();
    for (int o = 1; o < 256; o <<= 1) {
        int x = (t >= o) ? sh[t - o] : 0;
        __syncthreads();
        sh[t] += x;
        __syncthreads();
    }
    int prev = (t > 0) ? sh[t - 1] : 0;
    #pragma unroll
    for (int j = 0; j < 8; ++j)
        if (base + j < n) off[base + j] = prev + v[j];
    if (t == 255) bsum[blockIdx.x] = sh[255];
}

// single-wave shuffle scan (NB_SCAN=49 <= 64)
__global__ void scan2_kernel(int* bsum, int nb) {
    int lane = threadIdx.x;
    int orig = (lane < nb) ? bsum[lane] : 0;
    int v = orig;
    #pragma unroll
    for (int o = 1; o < 64; o <<= 1) {
        int t = __shfl_up(v, o);
        if (lane >= o) v += t;
    }
    if (lane < nb) bsum[lane] = v - orig;   // exclusive
}

__global__ void scan3_kernel(int* __restrict__ off, const int* __restrict__ bsum,
                             int* __restrict__ cur, int n, int E) {
    int i = blockIdx.x * blockDim.x + threadIdx.x;
    if (i < n) {
        int o = off[i] + bsum[i / SCAN_CHUNK];
        off[i] = o;
        cur[i] = o;
    } else if (i == n) {
        off[n] = E;
    }
}

// ---------------- CSR scatter ----------------
__global__ void scatter_kernel(const int* __restrict__ row, const int* __restrict__ col,
                               int* __restrict__ cur, int* __restrict__ srt, int E) {
    int i = blockIdx.x * blockDim.x + threadIdx.x;
    int stride = gridDim.x * blockDim.x;
    for (int e = i; e < E; e += stride) {
        int c = col[e];
        int p = atomicAdd(&cur[c], 1);
        srt[p] = row[e];
    }
}

// ---------------- W split-transpose setup ----------------
// wt1[ch][k] for ch<128, k<192 (k>=165 zero); wt2[ch][k] for ch<64, k<128
__global__ void wsplit_kernel(const float* __restrict__ W1, const float* __restrict__ W2,
                              ushort_t* __restrict__ wt1h, ushort_t* __restrict__ wt1l,
                              ushort_t* __restrict__ wt2h, ushort_t* __restrict__ wt2l) {
    int i = blockIdx.x * 256 + threadIdx.x;
    if (i < 128 * 192) {
        int ch = i / 192, k = i - ch * 192;
        float v = (k < IN_CH) ? W1[(size_t)k * 128 + ch] : 0.f;
        ushort_t h = f2bf(v);
        wt1h[i] = h;
        wt1l[i] = f2bf(v - bf2f(h));
    } else if (i < 128 * 192 + 64 * 128) {
        int j = i - 128 * 192;
        int ch = j / 128, k = j - ch * 128;
        float v = W2[(size_t)k * 64 + ch];
        ushort_t h = f2bf(v);
        wt2h[j] = h;
        wt2l[j] = f2bf(v - bf2f(h));
    }
}

// ---------------- MFMA GEMM: M[n][NOUT] = dis[n] * (X[n][KTOT] @ W[KTOT][NOUT]) ----
// split-bf16: x*w ~= xh*wh + xh*wl + xl*wh, fp32 accumulate.
// 4 waves/block, wave w -> nodes [w*16, w*16+16), NCT column tiles of 16.
// A-frag: lane l holds A[l&15][(l>>4)*8 + i]; B-frag: lane l holds B[(l>>4)*8+i][l&15]
// (B stored transposed in LDS as wt[ch][k] so the frag is a contiguous b128).
// C/D: row=(l>>4)*4+j, col=l&15  [m89-verified]
template<int NOUT, int KTOT, int KPAD>
__launch_bounds__(256)
__global__ void mfma_gemm_kernel(const float* __restrict__ X,
                                 const ushort_t* __restrict__ wth,
                                 const ushort_t* __restrict__ wtl,
                                 const float* __restrict__ dis,
                                 float* __restrict__ M, int n_nodes) {
    constexpr int NCT = NOUT / 16;
    constexpr int NCHUNK = KPAD / 32;
    __shared__ ushort_t xsh[64][32];
    __shared__ ushort_t xsl[64][32];
    __shared__ ushort_t wsh[NOUT][32];
    __shared__ ushort_t wsl[NOUT][32];

    int t = threadIdx.x;
    int l = t & 63, wid = t >> 6;
    long node0 = (long)blockIdx.x * 64;

    int arow = wid * 16 + (l & 15);
    int kq = (l >> 4) * 8;

    f32x4 acc[NCT];
    #pragma unroll
    for (int ct = 0; ct < NCT; ++ct) acc[ct] = (f32x4){0.f, 0.f, 0.f, 0.f};

    for (int c = 0; c < NCHUNK; ++c) {
        int k0 = c * 32;
        __syncthreads();
        // stage X chunk: 64 nodes x 32 k, split to bf16 hi/lo
        for (int idx = t; idx < 64 * 32; idx += 256) {
            int node = idx >> 5, kk = idx & 31;
            int k = k0 + kk;
            long g = node0 + node;
            float v = (g < n_nodes && k < KTOT) ? X[g * KTOT + k] : 0.f;
            ushort_t h = f2bf(v);
            xsh[node][kk] = h;
            xsl[node][kk] = f2bf(v - bf2f(h));
        }
        // stage W chunk: NOUT rows x 32 k (pre-split, pre-transposed, padded)
        for (int idx = t; idx < NOUT * 4; idx += 256) {
            int ch = idx >> 2, q = idx & 3;
            *(bfrag8*)&wsh[ch][q * 8] = *(const bfrag8*)&wth[(size_t)ch * KPAD + k0 + q * 8];
            *(bfrag8*)&wsl[ch][q * 8] = *(const bfrag8*)&wtl[(size_t)ch * KPAD + k0 + q * 8];
        }
        __syncthreads();

        bfrag8 ah = *(const bfrag8*)&xsh[arow][kq];
        bfrag8 al = *(const bfrag8*)&xsl[arow][kq];
        #pragma unroll
        for (int ct = 0; ct < NCT; ++ct) {
            bfrag8 bh = *(const bfrag8*)&wsh[ct * 16 + (l & 15)][kq];
            bfrag8 bl = *(const bfrag8*)&wsl[ct * 16 + (l & 15)][kq];
            acc[ct] = __builtin_amdgcn_mfma_f32_16x16x32_bf16(ah, bh, acc[ct], 0, 0, 0);
            acc[ct] = __builtin_amdgcn_mfma_f32_16x16x32_bf16(ah, bl, acc[ct], 0, 0, 0);
            acc[ct] = __builtin_amdgcn_mfma_f32_16x16x32_bf16(al, bh, acc[ct], 0, 0, 0);
        }
    }

    // epilogue: scale by dis[node], write M
    int nl = wid * 16 + (l >> 4) * 4;
    float dv[4];
    #pragma unroll
    for (int j = 0; j < 4; ++j) {
        long node = node0 + nl + j;
        dv[j] = (node < n_nodes) ? dis[node] : 0.f;
    }
    #pragma unroll
    for (int ct = 0; ct < NCT; ++ct) {
        int ch = ct * 16 + (l & 15);
        #pragma unroll
        for (int j = 0; j < 4; ++j) {
            long node = node0 + nl + j;
            if (node < n_nodes)
                M[node * NOUT + ch] = acc[ct][j] * dv[j];
        }
    }
}

// ---------------- aggregation layer 1: 128 ch, wave-per-node ----------------
// ms is pre-scaled by dis[src]; out = relu(dn * (ms[n] + sum ms[src]) + b1)
__global__ void agg1_kernel(const float* __restrict__ ms, const int* __restrict__ srt,
                            const int* __restrict__ off, const float* __restrict__ dis,
                            const float* __restrict__ b1, float* __restrict__ h1) {
    int wave = threadIdx.x >> 6;
    int lane = threadIdx.x & 63;
    int n = blockIdx.x * 4 + wave;
    if (n >= N_NODES) return;
    float dn = dis[n];
    float2 a = ((const float2*)(ms + (size_t)n * 128))[lane];
    float accx = a.x, accy = a.y;
    int s0 = off[n], s1 = off[n + 1];
    for (int base = s0; base < s1; base += 64) {
        int sv = (base + lane < s1) ? srt[base + lane] : 0;
        int cnt = min(64, s1 - base);
        int j = 0;
        for (; j + 7 < cnt; j += 8) {
            float2 v0 = ((const float2*)(ms + (size_t)__builtin_amdgcn_readlane(sv, j + 0) * 128))[lane];
            float2 v1 = ((const float2*)(ms + (size_t)__builtin_amdgcn_readlane(sv, j + 1) * 128))[lane];
            float2 v2 = ((const float2*)(ms + (size_t)__builtin_amdgcn_readlane(sv, j + 2) * 128))[lane];
            float2 v3 = ((const float2*)(ms + (size_t)__builtin_amdgcn_readlane(sv, j + 3) * 128))[lane];
            float2 v4 = ((const float2*)(ms + (size_t)__builtin_amdgcn_readlane(sv, j + 4) * 128))[lane];
            float2 v5 = ((const float2*)(ms + (size_t)__builtin_amdgcn_readlane(sv, j + 5) * 128))[lane];
            float2 v6 = ((const float2*)(ms + (size_t)__builtin_amdgcn_readlane(sv, j + 6) * 128))[lane];
            float2 v7 = ((const float2*)(ms + (size_t)__builtin_amdgcn_readlane(sv, j + 7) * 128))[lane];
            accx += v0.x + v1.x + v2.x + v3.x + v4.x + v5.x + v6.x + v7.x;
            accy += v0.y + v1.y + v2.y + v3.y + v4.y + v5.y + v6.y + v7.y;
        }
        for (; j < cnt; ++j) {
            int s = __builtin_amdgcn_readlane(sv, j);
            float2 v = ((const float2*)(ms + (size_t)s * 128))[lane];
            accx += v.x; accy += v.y;
        }
    }
    float2 b = ((const float2*)b1)[lane];
    float rx = fmaxf(accx * dn + b.x, 0.f);
    float ry = fmaxf(accy * dn + b.y, 0.f);
    ((float2*)(h1 + (size_t)n * 128))[lane] = make_float2(rx, ry);
}

// ---------------- aggregation layer 2 (64 ch) + output GEMM (64 -> 2) ----------------
__global__ void agg2_kernel(const float* __restrict__ ms, const int* __restrict__ srt,
                            const int* __restrict__ off, const float* __restrict__ dis,
                            const float* __restrict__ b2, const float* __restrict__ Wo,
                            const float* __restrict__ bo, float* __restrict__ out) {
    int wave = threadIdx.x >> 6;
    int lane = threadIdx.x & 63;
    int n = blockIdx.x * 4 + wave;
    if (n >= N_NODES) return;
    float dn = dis[n];
    float acc = ms[(size_t)n * 64 + lane];
    int s0 = off[n], s1 = off[n + 1];
    for (int base = s0; base < s1; base += 64) {
        int sv = (base + lane < s1) ? srt[base + lane] : 0;
        int cnt = min(64, s1 - base);
        int j = 0;
        for (; j + 7 < cnt; j += 8) {
            float v0 = ms[(size_t)__builtin_amdgcn_readlane(sv, j + 0) * 64 + lane];
            float v1 = ms[(size_t)__builtin_amdgcn_readlane(sv, j + 1) * 64 + lane];
            float v2 = ms[(size_t)__builtin_amdgcn_readlane(sv, j + 2) * 64 + lane];
            float v3 = ms[(size_t)__builtin_amdgcn_readlane(sv, j + 3) * 64 + lane];
            float v4 = ms[(size_t)__builtin_amdgcn_readlane(sv, j + 4) * 64 + lane];
            float v5 = ms[(size_t)__builtin_amdgcn_readlane(sv, j + 5) * 64 + lane];
            float v6 = ms[(size_t)__builtin_amdgcn_readlane(sv, j + 6) * 64 + lane];
            float v7 = ms[(size_t)__builtin_amdgcn_readlane(sv, j + 7) * 64 + lane];
            acc += v0 + v1 + v2 + v3 + v4 + v5 + v6 + v7;
        }
        for (; j < cnt; ++j) {
            acc += ms[(size_t)__builtin_amdgcn_readlane(sv, j) * 64 + lane];
        }
    }
    float v = fmaxf(acc * dn + b2[lane], 0.f);
    float p0 = v * Wo[lane * 2];
    float p1 = v * Wo[lane * 2 + 1];
    #pragma unroll
    for (int o = 32; o > 0; o >>= 1) {
        p0 += __shfl_xor(p0, o);
        p1 += __shfl_xor(p1, o);
    }
    if (lane == 0) {
        out[(size_t)n * 2]     = p0 + bo[0];
        out[(size_t)n * 2 + 1] = p1 + bo[1];
    }
}

// ---------------- launch ----------------
extern "C" void kernel_launch(void* const* d_in, const int* in_sizes, int n_in,
                              void* d_out, int out_size, void* d_ws, size_t ws_size,
                              hipStream_t stream) {
    const float* x  = (const float*)d_in[0];
    const int*   ei = (const int*)d_in[1];
    const int*   row = ei;
    const int*   col = ei + N_EDGES;
    const float* W1 = (const float*)d_in[2];
    const float* b1 = (const float*)d_in[3];
    const float* W2 = (const float*)d_in[4];
    const float* b2 = (const float*)d_in[5];
    const float* Wo = (const float*)d_in[6];
    const float* bo = (const float*)d_in[7];
    float* out = (float*)d_out;

    char* base = (char*)d_ws;
    auto alloc = [&](size_t bytes) {
        char* p = base;
        base += (bytes + 255) & ~(size_t)255;
        return p;
    };
    int*      cnt  = (int*)alloc((size_t)N_NODES * 4);
    int*      off  = (int*)alloc((size_t)(N_NODES + 1) * 4);
    int*      cur  = (int*)alloc((size_t)N_NODES * 4);
    float*    dis  = (float*)alloc((size_t)N_NODES * 4);
    int*      bsum = (int*)alloc(256);
    int*      srt  = (int*)alloc((size_t)N_EDGES * 4);
    float*    m    = (float*)alloc((size_t)N_NODES * 128 * 4);   // m1, reused as m2
    float*    h1   = (float*)alloc((size_t)N_NODES * 128 * 4);
    ushort_t* wt1h = (ushort_t*)alloc((size_t)128 * 192 * 2);
    ushort_t* wt1l = (ushort_t*)alloc((size_t)128 * 192 * 2);
    ushort_t* wt2h = (ushort_t*)alloc((size_t)64 * 128 * 2);
    ushort_t* wt2l = (ushort_t*)alloc((size_t)64 * 128 * 2);

    hipMemsetAsync(cnt, 0, (size_t)N_NODES * 4, stream);
    count_kernel<<<1024, 256, 0, stream>>>(col, cnt, N_EDGES);
    dis_kernel<<<(N_NODES + 255) / 256, 256, 0, stream>>>(cnt, dis, N_NODES);
    scan1_kernel<<<NB_SCAN, 256, 0, stream>>>(cnt, off, bsum, N_NODES);
    scan2_kernel<<<1, 64, 0, stream>>>(bsum, NB_SCAN);
    scan3_kernel<<<(N_NODES + 256) / 256, 256, 0, stream>>>(off, bsum, cur, N_NODES, N_EDGES);
    scatter_kernel<<<1024, 256, 0, stream>>>(row, col, cur, srt, N_EDGES);
    wsplit_kernel<<<(128 * 192 + 64 * 128 + 255) / 256, 256, 0, stream>>>(W1, W2, wt1h, wt1l, wt2h, wt2l);

    // layer 1: m = dis * (x @ W1)  [MFMA split-bf16]
    mfma_gemm_kernel<128, 165, 192><<<(N_NODES + 63) / 64, 256, 0, stream>>>(x, wt1h, wt1l, dis, m, N_NODES);
    agg1_kernel<<<(N_NODES + 3) / 4, 256, 0, stream>>>(m, srt, off, dis, b1, h1);

    // layer 2: m = dis * (h1 @ W2)  [MFMA split-bf16]
    mfma_gemm_kernel<64, 128, 128><<<(N_NODES + 63) / 64, 256, 0, stream>>>(h1, wt2h, wt2l, dis, m, N_NODES);
    agg2_kernel<<<(N_NODES + 3) / 4, 256, 0, stream>>>(m, srt, off, dis, b2, Wo, bo, out);
}

// Round 6
// 388.714 us; speedup vs baseline: 1.5285x; 1.2319x over previous
//
#include <hip/hip_runtime.h>

#define N_NODES 100000
#define N_EDGES 1600000
#define IN_CH   165
#define SCAN_CHUNK 2048   // 256 threads * 8 elems
#define NB_SCAN ((N_NODES + SCAN_CHUNK - 1) / SCAN_CHUNK)
#define BSHIFT 7
#define NBUCK  ((N_NODES + 127) / 128)   // 782
#define PA_BLOCKS 196

typedef unsigned short ushort_t;
typedef short bfrag8 __attribute__((ext_vector_type(8)));   // 8 bf16 (4 VGPRs)
typedef float f32x4 __attribute__((ext_vector_type(4)));

// bf16 round-to-nearest-even
__device__ __forceinline__ ushort_t f2bf(float f) {
    unsigned u = __float_as_uint(f);
    unsigned r = (u + 0x7fffu + ((u >> 16) & 1u)) >> 16;
    return (ushort_t)r;
}
__device__ __forceinline__ float bf2f(ushort_t h) {
    return __uint_as_float(((unsigned)h) << 16);
}

// ---------------- degree / norm ----------------
__global__ void count_kernel(const int* __restrict__ col, int* __restrict__ cnt, int E) {
    int i = blockIdx.x * blockDim.x + threadIdx.x;
    int stride = gridDim.x * blockDim.x;
    for (int e = i; e < E; e += stride) atomicAdd(&cnt[col[e]], 1);
}

__global__ void dis_kernel(const int* __restrict__ cnt, float* __restrict__ dis, int n) {
    int i = blockIdx.x * blockDim.x + threadIdx.x;
    if (i < n) dis[i] = rsqrtf((float)(cnt[i] + 1));   // +1 = self loop
}

// ---------------- exclusive scan (3 kernels) ----------------
__global__ void scan1_kernel(const int* __restrict__ cnt, int* __restrict__ off,
                             int* __restrict__ bsum, int n) {
    __shared__ int sh[256];
    int t = threadIdx.x;
    int base = blockIdx.x * SCAN_CHUNK + t * 8;
    int v[8];
    int run = 0;
    #pragma unroll
    for (int j = 0; j < 8; ++j) {
        int c = (base + j < n) ? cnt[base + j] : 0;
        v[j] = run; run += c;
    }
    sh[t] = run;
    __syncthreads();
    for (int o = 1; o < 256; o <<= 1) {
        int x = (t >= o) ? sh[t - o] : 0;
        __syncthreads();
        sh[t] += x;
        __syncthreads();
    }
    int prev = (t > 0) ? sh[t - 1] : 0;
    #pragma unroll
    for (int j = 0; j < 8; ++j)
        if (base + j < n) off[base + j] = prev + v[j];
    if (t == 255) bsum[blockIdx.x] = sh[255];
}

// single-wave shuffle scan (NB_SCAN=49 <= 64)
__global__ void scan2_kernel(int* bsum, int nb) {
    int lane = threadIdx.x;
    int orig = (lane < nb) ? bsum[lane] : 0;
    int v = orig;
    #pragma unroll
    for (int o = 1; o < 64; o <<= 1) {
        int t = __shfl_up(v, o);
        if (lane >= o) v += t;
    }
    if (lane < nb) bsum[lane] = v - orig;   // exclusive
}

__global__ void scan3_kernel(int* __restrict__ off, const int* __restrict__ bsum,
                             int n, int E) {
    int i = blockIdx.x * blockDim.x + threadIdx.x;
    if (i < n) {
        off[i] = off[i] + bsum[i / SCAN_CHUNK];
    } else if (i == n) {
        off[n] = E;
    }
}

// ---------------- bucketed CSR build ----------------
__global__ void binit_kernel(const int* __restrict__ off, int* __restrict__ bcur) {
    int b = blockIdx.x * 256 + threadIdx.x;
    if (b < NBUCK) bcur[b] = off[b << BSHIFT];
}

// Phase A: coarse scatter into bucket regions (dense runs per block)
__global__ void bucketA_kernel(const int* __restrict__ row, const int* __restrict__ col,
                               int* __restrict__ bcur, unsigned* __restrict__ tmp) {
    __shared__ int lcnt[NBUCK];
    __shared__ int lcur[NBUCK];
    int t = threadIdx.x;
    int e0 = (int)((long)blockIdx.x * N_EDGES / PA_BLOCKS);
    int e1 = (int)((long)(blockIdx.x + 1) * N_EDGES / PA_BLOCKS);
    for (int i = t; i < NBUCK; i += 256) lcnt[i] = 0;
    __syncthreads();
    for (int e = e0 + t; e < e1; e += 256)
        atomicAdd(&lcnt[col[e] >> BSHIFT], 1);
    __syncthreads();
    for (int b = t; b < NBUCK; b += 256) {
        int c = lcnt[b];
        lcur[b] = (c > 0) ? atomicAdd(&bcur[b], c) : 0;
    }
    __syncthreads();
    for (int e = e0 + t; e < e1; e += 256) {
        int cc = col[e];
        int b = cc >> BSHIFT;
        int p = atomicAdd(&lcur[b], 1);
        tmp[p] = ((unsigned)(cc & 127) << 17) | (unsigned)row[e];
    }
}

// Phase B: fine sort within each bucket region (L2-resident, dense writes)
__global__ void bucketB_kernel(const unsigned* __restrict__ tmp, const int* __restrict__ off,
                               int* __restrict__ srt) {
    __shared__ int lcur[128];
    int b = blockIdx.x;
    int t = threadIdx.x;
    int nb0 = b << BSHIFT;
    int hi = min(nb0 + 128, N_NODES);
    int base = off[nb0];
    if (t < 128) {
        int nn = nb0 + t;
        lcur[t] = (nn < hi) ? off[nn] - base : 0;
    }
    __syncthreads();
    int end = off[hi];
    for (int i = base + t; i < end; i += 256) {
        unsigned e = tmp[i];
        int c = (e >> 17) & 127;
        int r = (int)(e & 0x1FFFFu);
        int p = atomicAdd(&lcur[c], 1);
        srt[base + p] = r;
    }
}

// ---------------- W split-transpose setup ----------------
// wt1[ch][k] for ch<128, k<192 (k>=165 zero); wt2[ch][k] for ch<64, k<128
__global__ void wsplit_kernel(const float* __restrict__ W1, const float* __restrict__ W2,
                              ushort_t* __restrict__ wt1h, ushort_t* __restrict__ wt1l,
                              ushort_t* __restrict__ wt2h, ushort_t* __restrict__ wt2l) {
    int i = blockIdx.x * 256 + threadIdx.x;
    if (i < 128 * 192) {
        int ch = i / 192, k = i - ch * 192;
        float v = (k < IN_CH) ? W1[(size_t)k * 128 + ch] : 0.f;
        ushort_t h = f2bf(v);
        wt1h[i] = h;
        wt1l[i] = f2bf(v - bf2f(h));
    } else if (i < 128 * 192 + 64 * 128) {
        int j = i - 128 * 192;
        int ch = j / 128, k = j - ch * 128;
        float v = W2[(size_t)k * 64 + ch];
        ushort_t h = f2bf(v);
        wt2h[j] = h;
        wt2l[j] = f2bf(v - bf2f(h));
    }
}

// ---------------- MFMA GEMM: M[n][NOUT] = dis[n] * (X[n][KTOT] @ W[KTOT][NOUT]) ----
// split-bf16: x*w ~= xh*wh + xh*wl + xl*wh, fp32 accumulate.
template<int NOUT, int KTOT, int KPAD>
__launch_bounds__(256)
__global__ void mfma_gemm_kernel(const float* __restrict__ X,
                                 const ushort_t* __restrict__ wth,
                                 const ushort_t* __restrict__ wtl,
                                 const float* __restrict__ dis,
                                 float* __restrict__ M, int n_nodes) {
    constexpr int NCT = NOUT / 16;
    constexpr int NCHUNK = KPAD / 32;
    __shared__ ushort_t xsh[64][32];
    __shared__ ushort_t xsl[64][32];
    __shared__ ushort_t wsh[NOUT][32];
    __shared__ ushort_t wsl[NOUT][32];

    int t = threadIdx.x;
    int l = t & 63, wid = t >> 6;
    long node0 = (long)blockIdx.x * 64;

    int arow = wid * 16 + (l & 15);
    int kq = (l >> 4) * 8;

    f32x4 acc[NCT];
    #pragma unroll
    for (int ct = 0; ct < NCT; ++ct) acc[ct] = (f32x4){0.f, 0.f, 0.f, 0.f};

    for (int c = 0; c < NCHUNK; ++c) {
        int k0 = c * 32;
        __syncthreads();
        for (int idx = t; idx < 64 * 32; idx += 256) {
            int node = idx >> 5, kk = idx & 31;
            int k = k0 + kk;
            long g = node0 + node;
            float v = (g < n_nodes && k < KTOT) ? X[g * KTOT + k] : 0.f;
            ushort_t h = f2bf(v);
            xsh[node][kk] = h;
            xsl[node][kk] = f2bf(v - bf2f(h));
        }
        for (int idx = t; idx < NOUT * 4; idx += 256) {
            int ch = idx >> 2, q = idx & 3;
            *(bfrag8*)&wsh[ch][q * 8] = *(const bfrag8*)&wth[(size_t)ch * KPAD + k0 + q * 8];
            *(bfrag8*)&wsl[ch][q * 8] = *(const bfrag8*)&wtl[(size_t)ch * KPAD + k0 + q * 8];
        }
        __syncthreads();

        bfrag8 ah = *(const bfrag8*)&xsh[arow][kq];
        bfrag8 al = *(const bfrag8*)&xsl[arow][kq];
        #pragma unroll
        for (int ct = 0; ct < NCT; ++ct) {
            bfrag8 bh = *(const bfrag8*)&wsh[ct * 16 + (l & 15)][kq];
            bfrag8 bl = *(const bfrag8*)&wsl[ct * 16 + (l & 15)][kq];
            acc[ct] = __builtin_amdgcn_mfma_f32_16x16x32_bf16(ah, bh, acc[ct], 0, 0, 0);
            acc[ct] = __builtin_amdgcn_mfma_f32_16x16x32_bf16(ah, bl, acc[ct], 0, 0, 0);
            acc[ct] = __builtin_amdgcn_mfma_f32_16x16x32_bf16(al, bh, acc[ct], 0, 0, 0);
        }
    }

    int nl = wid * 16 + (l >> 4) * 4;
    float dv[4];
    #pragma unroll
    for (int j = 0; j < 4; ++j) {
        long node = node0 + nl + j;
        dv[j] = (node < n_nodes) ? dis[node] : 0.f;
    }
    #pragma unroll
    for (int ct = 0; ct < NCT; ++ct) {
        int ch = ct * 16 + (l & 15);
        #pragma unroll
        for (int j = 0; j < 4; ++j) {
            long node = node0 + nl + j;
            if (node < n_nodes)
                M[node * NOUT + ch] = acc[ct][j] * dv[j];
        }
    }
}

// ---------------- aggregation layer 1: 128 ch, wave-per-node ----------------
__global__ void agg1_kernel(const float* __restrict__ ms, const int* __restrict__ srt,
                            const int* __restrict__ off, const float* __restrict__ dis,
                            const float* __restrict__ b1, float* __restrict__ h1) {
    int wave = threadIdx.x >> 6;
    int lane = threadIdx.x & 63;
    int n = blockIdx.x * 4 + wave;
    if (n >= N_NODES) return;
    float dn = dis[n];
    float2 a = ((const float2*)(ms + (size_t)n * 128))[lane];
    float accx = a.x, accy = a.y;
    int s0 = off[n], s1 = off[n + 1];
    for (int base = s0; base < s1; base += 64) {
        int sv = (base + lane < s1) ? srt[base + lane] : 0;
        int cnt = min(64, s1 - base);
        int j = 0;
        for (; j + 7 < cnt; j += 8) {
            float2 v0 = ((const float2*)(ms + (size_t)__builtin_amdgcn_readlane(sv, j + 0) * 128))[lane];
            float2 v1 = ((const float2*)(ms + (size_t)__builtin_amdgcn_readlane(sv, j + 1) * 128))[lane];
            float2 v2 = ((const float2*)(ms + (size_t)__builtin_amdgcn_readlane(sv, j + 2) * 128))[lane];
            float2 v3 = ((const float2*)(ms + (size_t)__builtin_amdgcn_readlane(sv, j + 3) * 128))[lane];
            float2 v4 = ((const float2*)(ms + (size_t)__builtin_amdgcn_readlane(sv, j + 4) * 128))[lane];
            float2 v5 = ((const float2*)(ms + (size_t)__builtin_amdgcn_readlane(sv, j + 5) * 128))[lane];
            float2 v6 = ((const float2*)(ms + (size_t)__builtin_amdgcn_readlane(sv, j + 6) * 128))[lane];
            float2 v7 = ((const float2*)(ms + (size_t)__builtin_amdgcn_readlane(sv, j + 7) * 128))[lane];
            accx += v0.x + v1.x + v2.x + v3.x + v4.x + v5.x + v6.x + v7.x;
            accy += v0.y + v1.y + v2.y + v3.y + v4.y + v5.y + v6.y + v7.y;
        }
        for (; j < cnt; ++j) {
            int s = __builtin_amdgcn_readlane(sv, j);
            float2 v = ((const float2*)(ms + (size_t)s * 128))[lane];
            accx += v.x; accy += v.y;
        }
    }
    float2 b = ((const float2*)b1)[lane];
    float rx = fmaxf(accx * dn + b.x, 0.f);
    float ry = fmaxf(accy * dn + b.y, 0.f);
    ((float2*)(h1 + (size_t)n * 128))[lane] = make_float2(rx, ry);
}

// ---------------- aggregation layer 2 (64 ch) + output GEMM (64 -> 2) ----------------
__global__ void agg2_kernel(const float* __restrict__ ms, const int* __restrict__ srt,
                            const int* __restrict__ off, const float* __restrict__ dis,
                            const float* __restrict__ b2, const float* __restrict__ Wo,
                            const float* __restrict__ bo, float* __restrict__ out) {
    int wave = threadIdx.x >> 6;
    int lane = threadIdx.x & 63;
    int n = blockIdx.x * 4 + wave;
    if (n >= N_NODES) return;
    float dn = dis[n];
    float acc = ms[(size_t)n * 64 + lane];
    int s0 = off[n], s1 = off[n + 1];
    for (int base = s0; base < s1; base += 64) {
        int sv = (base + lane < s1) ? srt[base + lane] : 0;
        int cnt = min(64, s1 - base);
        int j = 0;
        for (; j + 7 < cnt; j += 8) {
            float v0 = ms[(size_t)__builtin_amdgcn_readlane(sv, j + 0) * 64 + lane];
            float v1 = ms[(size_t)__builtin_amdgcn_readlane(sv, j + 1) * 64 + lane];
            float v2 = ms[(size_t)__builtin_amdgcn_readlane(sv, j + 2) * 64 + lane];
            float v3 = ms[(size_t)__builtin_amdgcn_readlane(sv, j + 3) * 64 + lane];
            float v4 = ms[(size_t)__builtin_amdgcn_readlane(sv, j + 4) * 64 + lane];
            float v5 = ms[(size_t)__builtin_amdgcn_readlane(sv, j + 5) * 64 + lane];
            float v6 = ms[(size_t)__builtin_amdgcn_readlane(sv, j + 6) * 64 + lane];
            float v7 = ms[(size_t)__builtin_amdgcn_readlane(sv, j + 7) * 64 + lane];
            acc += v0 + v1 + v2 + v3 + v4 + v5 + v6 + v7;
        }
        for (; j < cnt; ++j) {
            acc += ms[(size_t)__builtin_amdgcn_readlane(sv, j) * 64 + lane];
        }
    }
    float v = fmaxf(acc * dn + b2[lane], 0.f);
    float p0 = v * Wo[lane * 2];
    float p1 = v * Wo[lane * 2 + 1];
    #pragma unroll
    for (int o = 32; o > 0; o >>= 1) {
        p0 += __shfl_xor(p0, o);
        p1 += __shfl_xor(p1, o);
    }
    if (lane == 0) {
        out[(size_t)n * 2]     = p0 + bo[0];
        out[(size_t)n * 2 + 1] = p1 + bo[1];
    }
}

// ---------------- launch ----------------
extern "C" void kernel_launch(void* const* d_in, const int* in_sizes, int n_in,
                              void* d_out, int out_size, void* d_ws, size_t ws_size,
                              hipStream_t stream) {
    const float* x  = (const float*)d_in[0];
    const int*   ei = (const int*)d_in[1];
    const int*   row = ei;
    const int*   col = ei + N_EDGES;
    const float* W1 = (const float*)d_in[2];
    const float* b1 = (const float*)d_in[3];
    const float* W2 = (const float*)d_in[4];
    const float* b2 = (const float*)d_in[5];
    const float* Wo = (const float*)d_in[6];
    const float* bo = (const float*)d_in[7];
    float* out = (float*)d_out;

    char* base = (char*)d_ws;
    auto alloc = [&](size_t bytes) {
        char* p = base;
        base += (bytes + 255) & ~(size_t)255;
        return p;
    };
    int*      cnt  = (int*)alloc((size_t)N_NODES * 4);
    int*      off  = (int*)alloc((size_t)(N_NODES + 1) * 4);
    float*    dis  = (float*)alloc((size_t)N_NODES * 4);
    int*      bsum = (int*)alloc(256);
    int*      bcur = (int*)alloc((size_t)NBUCK * 4);
    unsigned* tmp  = (unsigned*)alloc((size_t)N_EDGES * 4);
    int*      srt  = (int*)alloc((size_t)N_EDGES * 4);
    float*    m    = (float*)alloc((size_t)N_NODES * 128 * 4);   // m1, reused as m2
    float*    h1   = (float*)alloc((size_t)N_NODES * 128 * 4);
    ushort_t* wt1h = (ushort_t*)alloc((size_t)128 * 192 * 2);
    ushort_t* wt1l = (ushort_t*)alloc((size_t)128 * 192 * 2);
    ushort_t* wt2h = (ushort_t*)alloc((size_t)64 * 128 * 2);
    ushort_t* wt2l = (ushort_t*)alloc((size_t)64 * 128 * 2);

    hipMemsetAsync(cnt, 0, (size_t)N_NODES * 4, stream);
    count_kernel<<<1024, 256, 0, stream>>>(col, cnt, N_EDGES);
    dis_kernel<<<(N_NODES + 255) / 256, 256, 0, stream>>>(cnt, dis, N_NODES);
    scan1_kernel<<<NB_SCAN, 256, 0, stream>>>(cnt, off, bsum, N_NODES);
    scan2_kernel<<<1, 64, 0, stream>>>(bsum, NB_SCAN);
    scan3_kernel<<<(N_NODES + 256) / 256, 256, 0, stream>>>(off, bsum, N_NODES, N_EDGES);
    binit_kernel<<<(NBUCK + 255) / 256, 256, 0, stream>>>(off, bcur);
    bucketA_kernel<<<PA_BLOCKS, 256, 0, stream>>>(row, col, bcur, tmp);
    bucketB_kernel<<<NBUCK, 256, 0, stream>>>(tmp, off, srt);
    wsplit_kernel<<<(128 * 192 + 64 * 128 + 255) / 256, 256, 0, stream>>>(W1, W2, wt1h, wt1l, wt2h, wt2l);

    // layer 1: m = dis * (x @ W1)  [MFMA split-bf16]
    mfma_gemm_kernel<128, 165, 192><<<(N_NODES + 63) / 64, 256, 0, stream>>>(x, wt1h, wt1l, dis, m, N_NODES);
    agg1_kernel<<<(N_NODES + 3) / 4, 256, 0, stream>>>(m, srt, off, dis, b1, h1);

    // layer 2: m = dis * (h1 @ W2)  [MFMA split-bf16]
    mfma_gemm_kernel<64, 128, 128><<<(N_NODES + 63) / 64, 256, 0, stream>>>(h1, wt2h, wt2l, dis, m, N_NODES);
    agg2_kernel<<<(N_NODES + 3) / 4, 256, 0, stream>>>(m, srt, off, dis, b2, Wo, bo, out);
}

// Round 7
// 326.396 us; speedup vs baseline: 1.8203x; 1.1909x over previous
//
#include <hip/hip_runtime.h>

#define N_NODES 100000
#define N_EDGES 1600000
#define IN_CH   165
#define SCAN_CHUNK 2048   // 256 threads * 8 elems
#define NB_SCAN ((N_NODES + SCAN_CHUNK - 1) / SCAN_CHUNK)
#define BSHIFT 7
#define NBUCK  ((N_NODES + 127) / 128)   // 782
#define PA_BLOCKS 196

typedef unsigned short ushort_t;
typedef _Float16 f16;
typedef _Float16 f16x2 __attribute__((ext_vector_type(2)));
typedef short bfrag8 __attribute__((ext_vector_type(8)));   // 8 bf16 (4 VGPRs)
typedef float f32x4 __attribute__((ext_vector_type(4)));

// bf16 round-to-nearest-even
__device__ __forceinline__ ushort_t f2bf(float f) {
    unsigned u = __float_as_uint(f);
    unsigned r = (u + 0x7fffu + ((u >> 16) & 1u)) >> 16;
    return (ushort_t)r;
}
__device__ __forceinline__ float bf2f(ushort_t h) {
    return __uint_as_float(((unsigned)h) << 16);
}

// ---------------- degree / norm ----------------
__global__ void count_kernel(const int* __restrict__ col, int* __restrict__ cnt, int E) {
    int i = blockIdx.x * blockDim.x + threadIdx.x;
    int stride = gridDim.x * blockDim.x;
    for (int e = i; e < E; e += stride) atomicAdd(&cnt[col[e]], 1);
}

__global__ void dis_kernel(const int* __restrict__ cnt, float* __restrict__ dis, int n) {
    int i = blockIdx.x * blockDim.x + threadIdx.x;
    if (i < n) dis[i] = rsqrtf((float)(cnt[i] + 1));   // +1 = self loop
}

// ---------------- exclusive scan (3 kernels) ----------------
__global__ void scan1_kernel(const int* __restrict__ cnt, int* __restrict__ off,
                             int* __restrict__ bsum, int n) {
    __shared__ int sh[256];
    int t = threadIdx.x;
    int base = blockIdx.x * SCAN_CHUNK + t * 8;
    int v[8];
    int run = 0;
    #pragma unroll
    for (int j = 0; j < 8; ++j) {
        int c = (base + j < n) ? cnt[base + j] : 0;
        v[j] = run; run += c;
    }
    sh[t] = run;
    __syncthreads();
    for (int o = 1; o < 256; o <<= 1) {
        int x = (t >= o) ? sh[t - o] : 0;
        __syncthreads();
        sh[t] += x;
        __syncthreads();
    }
    int prev = (t > 0) ? sh[t - 1] : 0;
    #pragma unroll
    for (int j = 0; j < 8; ++j)
        if (base + j < n) off[base + j] = prev + v[j];
    if (t == 255) bsum[blockIdx.x] = sh[255];
}

// single-wave shuffle scan (NB_SCAN=49 <= 64)
__global__ void scan2_kernel(int* bsum, int nb) {
    int lane = threadIdx.x;
    int orig = (lane < nb) ? bsum[lane] : 0;
    int v = orig;
    #pragma unroll
    for (int o = 1; o < 64; o <<= 1) {
        int t = __shfl_up(v, o);
        if (lane >= o) v += t;
    }
    if (lane < nb) bsum[lane] = v - orig;   // exclusive
}

__global__ void scan3_kernel(int* __restrict__ off, const int* __restrict__ bsum,
                             int n, int E) {
    int i = blockIdx.x * blockDim.x + threadIdx.x;
    if (i < n) {
        off[i] = off[i] + bsum[i / SCAN_CHUNK];
    } else if (i == n) {
        off[n] = E;
    }
}

// ---------------- bucketed CSR build ----------------
__global__ void binit_kernel(const int* __restrict__ off, int* __restrict__ bcur) {
    int b = blockIdx.x * 256 + threadIdx.x;
    if (b < NBUCK) bcur[b] = off[b << BSHIFT];
}

// Phase A: coarse scatter into bucket regions (dense runs per block)
__global__ void bucketA_kernel(const int* __restrict__ row, const int* __restrict__ col,
                               int* __restrict__ bcur, unsigned* __restrict__ tmp) {
    __shared__ int lcnt[NBUCK];
    __shared__ int lcur[NBUCK];
    int t = threadIdx.x;
    int e0 = (int)((long)blockIdx.x * N_EDGES / PA_BLOCKS);
    int e1 = (int)((long)(blockIdx.x + 1) * N_EDGES / PA_BLOCKS);
    for (int i = t; i < NBUCK; i += 256) lcnt[i] = 0;
    __syncthreads();
    for (int e = e0 + t; e < e1; e += 256)
        atomicAdd(&lcnt[col[e] >> BSHIFT], 1);
    __syncthreads();
    for (int b = t; b < NBUCK; b += 256) {
        int c = lcnt[b];
        lcur[b] = (c > 0) ? atomicAdd(&bcur[b], c) : 0;
    }
    __syncthreads();
    for (int e = e0 + t; e < e1; e += 256) {
        int cc = col[e];
        int b = cc >> BSHIFT;
        int p = atomicAdd(&lcur[b], 1);
        tmp[p] = ((unsigned)(cc & 127) << 17) | (unsigned)row[e];
    }
}

// Phase B: fine sort within each bucket region (L2-resident, dense writes)
__global__ void bucketB_kernel(const unsigned* __restrict__ tmp, const int* __restrict__ off,
                               int* __restrict__ srt) {
    __shared__ int lcur[128];
    int b = blockIdx.x;
    int t = threadIdx.x;
    int nb0 = b << BSHIFT;
    int hi = min(nb0 + 128, N_NODES);
    int base = off[nb0];
    if (t < 128) {
        int nn = nb0 + t;
        lcur[t] = (nn < hi) ? off[nn] - base : 0;
    }
    __syncthreads();
    int end = off[hi];
    for (int i = base + t; i < end; i += 256) {
        unsigned e = tmp[i];
        int c = (e >> 17) & 127;
        int r = (int)(e & 0x1FFFFu);
        int p = atomicAdd(&lcur[c], 1);
        srt[base + p] = r;
    }
}

// ---------------- W split-transpose setup ----------------
// wt1[ch][k] for ch<128, k<192 (k>=165 zero); wt2[ch][k] for ch<64, k<128
__global__ void wsplit_kernel(const float* __restrict__ W1, const float* __restrict__ W2,
                              ushort_t* __restrict__ wt1h, ushort_t* __restrict__ wt1l,
                              ushort_t* __restrict__ wt2h, ushort_t* __restrict__ wt2l) {
    int i = blockIdx.x * 256 + threadIdx.x;
    if (i < 128 * 192) {
        int ch = i / 192, k = i - ch * 192;
        float v = (k < IN_CH) ? W1[(size_t)k * 128 + ch] : 0.f;
        ushort_t h = f2bf(v);
        wt1h[i] = h;
        wt1l[i] = f2bf(v - bf2f(h));
    } else if (i < 128 * 192 + 64 * 128) {
        int j = i - 128 * 192;
        int ch = j / 128, k = j - ch * 128;
        float v = W2[(size_t)k * 64 + ch];
        ushort_t h = f2bf(v);
        wt2h[j] = h;
        wt2l[j] = f2bf(v - bf2f(h));
    }
}

// ---------------- MFMA GEMM: M[n][NOUT] = dis[n] * (X[n][KTOT] @ W[KTOT][NOUT]) ----
// split-bf16: x*w ~= xh*wh + xh*wl + xl*wh, fp32 accumulate, fp16 output.
template<int NOUT, int KTOT, int KPAD>
__launch_bounds__(256)
__global__ void mfma_gemm_kernel(const float* __restrict__ X,
                                 const ushort_t* __restrict__ wth,
                                 const ushort_t* __restrict__ wtl,
                                 const float* __restrict__ dis,
                                 f16* __restrict__ M, int n_nodes) {
    constexpr int NCT = NOUT / 16;
    constexpr int NCHUNK = KPAD / 32;
    __shared__ ushort_t xsh[64][32];
    __shared__ ushort_t xsl[64][32];
    __shared__ ushort_t wsh[NOUT][32];
    __shared__ ushort_t wsl[NOUT][32];

    int t = threadIdx.x;
    int l = t & 63, wid = t >> 6;
    long node0 = (long)blockIdx.x * 64;

    int arow = wid * 16 + (l & 15);
    int kq = (l >> 4) * 8;

    f32x4 acc[NCT];
    #pragma unroll
    for (int ct = 0; ct < NCT; ++ct) acc[ct] = (f32x4){0.f, 0.f, 0.f, 0.f};

    for (int c = 0; c < NCHUNK; ++c) {
        int k0 = c * 32;
        __syncthreads();
        for (int idx = t; idx < 64 * 32; idx += 256) {
            int node = idx >> 5, kk = idx & 31;
            int k = k0 + kk;
            long g = node0 + node;
            float v = (g < n_nodes && k < KTOT) ? X[g * KTOT + k] : 0.f;
            ushort_t h = f2bf(v);
            xsh[node][kk] = h;
            xsl[node][kk] = f2bf(v - bf2f(h));
        }
        for (int idx = t; idx < NOUT * 4; idx += 256) {
            int ch = idx >> 2, q = idx & 3;
            *(bfrag8*)&wsh[ch][q * 8] = *(const bfrag8*)&wth[(size_t)ch * KPAD + k0 + q * 8];
            *(bfrag8*)&wsl[ch][q * 8] = *(const bfrag8*)&wtl[(size_t)ch * KPAD + k0 + q * 8];
        }
        __syncthreads();

        bfrag8 ah = *(const bfrag8*)&xsh[arow][kq];
        bfrag8 al = *(const bfrag8*)&xsl[arow][kq];
        #pragma unroll
        for (int ct = 0; ct < NCT; ++ct) {
            bfrag8 bh = *(const bfrag8*)&wsh[ct * 16 + (l & 15)][kq];
            bfrag8 bl = *(const bfrag8*)&wsl[ct * 16 + (l & 15)][kq];
            acc[ct] = __builtin_amdgcn_mfma_f32_16x16x32_bf16(ah, bh, acc[ct], 0, 0, 0);
            acc[ct] = __builtin_amdgcn_mfma_f32_16x16x32_bf16(ah, bl, acc[ct], 0, 0, 0);
            acc[ct] = __builtin_amdgcn_mfma_f32_16x16x32_bf16(al, bh, acc[ct], 0, 0, 0);
        }
    }

    int nl = wid * 16 + (l >> 4) * 4;
    float dv[4];
    #pragma unroll
    for (int j = 0; j < 4; ++j) {
        long node = node0 + nl + j;
        dv[j] = (node < n_nodes) ? dis[node] : 0.f;
    }
    #pragma unroll
    for (int ct = 0; ct < NCT; ++ct) {
        int ch = ct * 16 + (l & 15);
        #pragma unroll
        for (int j = 0; j < 4; ++j) {
            long node = node0 + nl + j;
            if (node < n_nodes)
                M[node * NOUT + ch] = (f16)(acc[ct][j] * dv[j]);
        }
    }
}

// ---------------- aggregation layer 1: 128 ch fp16, wave-per-node ----------------
// ms is pre-scaled by dis[src]; out = relu(dn * (ms[n] + sum ms[src]) + b1)
__global__ void agg1_kernel(const f16* __restrict__ ms, const int* __restrict__ srt,
                            const int* __restrict__ off, const float* __restrict__ dis,
                            const float* __restrict__ b1, float* __restrict__ h1) {
    int wave = threadIdx.x >> 6;
    int lane = threadIdx.x & 63;
    int n = blockIdx.x * 4 + wave;
    if (n >= N_NODES) return;
    float dn = dis[n];
    f16x2 a = ((const f16x2*)(ms + (size_t)n * 128))[lane];
    float accx = (float)a.x, accy = (float)a.y;
    int s0 = off[n], s1 = off[n + 1];
    for (int base = s0; base < s1; base += 64) {
        int sv = (base + lane < s1) ? srt[base + lane] : 0;
        int cnt = min(64, s1 - base);
        int j = 0;
        for (; j + 7 < cnt; j += 8) {
            f16x2 v0 = ((const f16x2*)(ms + (size_t)__builtin_amdgcn_readlane(sv, j + 0) * 128))[lane];
            f16x2 v1 = ((const f16x2*)(ms + (size_t)__builtin_amdgcn_readlane(sv, j + 1) * 128))[lane];
            f16x2 v2 = ((const f16x2*)(ms + (size_t)__builtin_amdgcn_readlane(sv, j + 2) * 128))[lane];
            f16x2 v3 = ((const f16x2*)(ms + (size_t)__builtin_amdgcn_readlane(sv, j + 3) * 128))[lane];
            f16x2 v4 = ((const f16x2*)(ms + (size_t)__builtin_amdgcn_readlane(sv, j + 4) * 128))[lane];
            f16x2 v5 = ((const f16x2*)(ms + (size_t)__builtin_amdgcn_readlane(sv, j + 5) * 128))[lane];
            f16x2 v6 = ((const f16x2*)(ms + (size_t)__builtin_amdgcn_readlane(sv, j + 6) * 128))[lane];
            f16x2 v7 = ((const f16x2*)(ms + (size_t)__builtin_amdgcn_readlane(sv, j + 7) * 128))[lane];
            accx += (float)v0.x + (float)v1.x + (float)v2.x + (float)v3.x
                  + (float)v4.x + (float)v5.x + (float)v6.x + (float)v7.x;
            accy += (float)v0.y + (float)v1.y + (float)v2.y + (float)v3.y
                  + (float)v4.y + (float)v5.y + (float)v6.y + (float)v7.y;
        }
        for (; j < cnt; ++j) {
            int s = __builtin_amdgcn_readlane(sv, j);
            f16x2 v = ((const f16x2*)(ms + (size_t)s * 128))[lane];
            accx += (float)v.x; accy += (float)v.y;
        }
    }
    float2 b = ((const float2*)b1)[lane];
    float rx = fmaxf(accx * dn + b.x, 0.f);
    float ry = fmaxf(accy * dn + b.y, 0.f);
    ((float2*)(h1 + (size_t)n * 128))[lane] = make_float2(rx, ry);
}

// ---------------- aggregation layer 2 (64 ch fp16) + output GEMM (64 -> 2) ----------------
__global__ void agg2_kernel(const f16* __restrict__ ms, const int* __restrict__ srt,
                            const int* __restrict__ off, const float* __restrict__ dis,
                            const float* __restrict__ b2, const float* __restrict__ Wo,
                            const float* __restrict__ bo, float* __restrict__ out) {
    int wave = threadIdx.x >> 6;
    int lane = threadIdx.x & 63;
    int n = blockIdx.x * 4 + wave;
    if (n >= N_NODES) return;
    float dn = dis[n];
    float acc = (float)ms[(size_t)n * 64 + lane];
    int s0 = off[n], s1 = off[n + 1];
    for (int base = s0; base < s1; base += 64) {
        int sv = (base + lane < s1) ? srt[base + lane] : 0;
        int cnt = min(64, s1 - base);
        int j = 0;
        for (; j + 7 < cnt; j += 8) {
            float v0 = (float)ms[(size_t)__builtin_amdgcn_readlane(sv, j + 0) * 64 + lane];
            float v1 = (float)ms[(size_t)__builtin_amdgcn_readlane(sv, j + 1) * 64 + lane];
            float v2 = (float)ms[(size_t)__builtin_amdgcn_readlane(sv, j + 2) * 64 + lane];
            float v3 = (float)ms[(size_t)__builtin_amdgcn_readlane(sv, j + 3) * 64 + lane];
            float v4 = (float)ms[(size_t)__builtin_amdgcn_readlane(sv, j + 4) * 64 + lane];
            float v5 = (float)ms[(size_t)__builtin_amdgcn_readlane(sv, j + 5) * 64 + lane];
            float v6 = (float)ms[(size_t)__builtin_amdgcn_readlane(sv, j + 6) * 64 + lane];
            float v7 = (float)ms[(size_t)__builtin_amdgcn_readlane(sv, j + 7) * 64 + lane];
            acc += v0 + v1 + v2 + v3 + v4 + v5 + v6 + v7;
        }
        for (; j < cnt; ++j) {
            acc += (float)ms[(size_t)__builtin_amdgcn_readlane(sv, j) * 64 + lane];
        }
    }
    float v = fmaxf(acc * dn + b2[lane], 0.f);
    float p0 = v * Wo[lane * 2];
    float p1 = v * Wo[lane * 2 + 1];
    #pragma unroll
    for (int o = 32; o > 0; o >>= 1) {
        p0 += __shfl_xor(p0, o);
        p1 += __shfl_xor(p1, o);
    }
    if (lane == 0) {
        out[(size_t)n * 2]     = p0 + bo[0];
        out[(size_t)n * 2 + 1] = p1 + bo[1];
    }
}

// ---------------- launch ----------------
extern "C" void kernel_launch(void* const* d_in, const int* in_sizes, int n_in,
                              void* d_out, int out_size, void* d_ws, size_t ws_size,
                              hipStream_t stream) {
    const float* x  = (const float*)d_in[0];
    const int*   ei = (const int*)d_in[1];
    const int*   row = ei;
    const int*   col = ei + N_EDGES;
    const float* W1 = (const float*)d_in[2];
    const float* b1 = (const float*)d_in[3];
    const float* W2 = (const float*)d_in[4];
    const float* b2 = (const float*)d_in[5];
    const float* Wo = (const float*)d_in[6];
    const float* bo = (const float*)d_in[7];
    float* out = (float*)d_out;

    char* base = (char*)d_ws;
    auto alloc = [&](size_t bytes) {
        char* p = base;
        base += (bytes + 255) & ~(size_t)255;
        return p;
    };
    int*      cnt  = (int*)alloc((size_t)N_NODES * 4);
    int*      off  = (int*)alloc((size_t)(N_NODES + 1) * 4);
    float*    dis  = (float*)alloc((size_t)N_NODES * 4);
    int*      bsum = (int*)alloc(256);
    int*      bcur = (int*)alloc((size_t)NBUCK * 4);
    unsigned* tmp  = (unsigned*)alloc((size_t)N_EDGES * 4);
    int*      srt  = (int*)alloc((size_t)N_EDGES * 4);
    f16*      m    = (f16*)alloc((size_t)N_NODES * 128 * 2);   // m1, reused as m2
    float*    h1   = (float*)alloc((size_t)N_NODES * 128 * 4);
    ushort_t* wt1h = (ushort_t*)alloc((size_t)128 * 192 * 2);
    ushort_t* wt1l = (ushort_t*)alloc((size_t)128 * 192 * 2);
    ushort_t* wt2h = (ushort_t*)alloc((size_t)64 * 128 * 2);
    ushort_t* wt2l = (ushort_t*)alloc((size_t)64 * 128 * 2);

    hipMemsetAsync(cnt, 0, (size_t)N_NODES * 4, stream);
    count_kernel<<<1024, 256, 0, stream>>>(col, cnt, N_EDGES);
    dis_kernel<<<(N_NODES + 255) / 256, 256, 0, stream>>>(cnt, dis, N_NODES);
    scan1_kernel<<<NB_SCAN, 256, 0, stream>>>(cnt, off, bsum, N_NODES);
    scan2_kernel<<<1, 64, 0, stream>>>(bsum, NB_SCAN);
    scan3_kernel<<<(N_NODES + 256) / 256, 256, 0, stream>>>(off, bsum, N_NODES, N_EDGES);
    binit_kernel<<<(NBUCK + 255) / 256, 256, 0, stream>>>(off, bcur);
    bucketA_kernel<<<PA_BLOCKS, 256, 0, stream>>>(row, col, bcur, tmp);
    bucketB_kernel<<<NBUCK, 256, 0, stream>>>(tmp, off, srt);
    wsplit_kernel<<<(128 * 192 + 64 * 128 + 255) / 256, 256, 0, stream>>>(W1, W2, wt1h, wt1l, wt2h, wt2l);

    // layer 1: m = dis * (x @ W1)  [MFMA split-bf16 -> fp16]
    mfma_gemm_kernel<128, 165, 192><<<(N_NODES + 63) / 64, 256, 0, stream>>>(x, wt1h, wt1l, dis, m, N_NODES);
    agg1_kernel<<<(N_NODES + 3) / 4, 256, 0, stream>>>(m, srt, off, dis, b1, h1);

    // layer 2: m = dis * (h1 @ W2)  [MFMA split-bf16 -> fp16]
    mfma_gemm_kernel<64, 128, 128><<<(N_NODES + 63) / 64, 256, 0, stream>>>(h1, wt2h, wt2l, dis, m, N_NODES);
    agg2_kernel<<<(N_NODES + 3) / 4, 256, 0, stream>>>(m, srt, off, dis, b2, Wo, bo, out);
}

// Round 8
// 310.475 us; speedup vs baseline: 1.9137x; 1.0513x over previous
//
#include <hip/hip_runtime.h>

#define N_NODES 100000
#define N_EDGES 1600000
#define IN_CH   165
#define SCAN_CHUNK 2048   // 256 threads * 8 elems
#define NB_SCAN ((N_NODES + SCAN_CHUNK - 1) / SCAN_CHUNK)
#define BSHIFT 7
#define NBUCK  ((N_NODES + 127) / 128)   // 782
#define PA_BLOCKS 196

typedef unsigned short ushort_t;
typedef _Float16 f16;
typedef _Float16 f16x2 __attribute__((ext_vector_type(2)));
typedef short bfrag8 __attribute__((ext_vector_type(8)));   // 8 bf16 (4 VGPRs)
typedef float f32x4 __attribute__((ext_vector_type(4)));

// bf16 round-to-nearest-even
__device__ __forceinline__ ushort_t f2bf(float f) {
    unsigned u = __float_as_uint(f);
    unsigned r = (u + 0x7fffu + ((u >> 16) & 1u)) >> 16;
    return (ushort_t)r;
}
__device__ __forceinline__ float bf2f(ushort_t h) {
    return __uint_as_float(((unsigned)h) << 16);
}

// ---------------- degree / norm ----------------
__global__ void count_kernel(const int* __restrict__ col, int* __restrict__ cnt, int E) {
    int i = blockIdx.x * blockDim.x + threadIdx.x;
    int stride = gridDim.x * blockDim.x;
    for (int e = i; e < E; e += stride) atomicAdd(&cnt[col[e]], 1);
}

__global__ void dis_kernel(const int* __restrict__ cnt, float* __restrict__ dis, int n) {
    int i = blockIdx.x * blockDim.x + threadIdx.x;
    if (i < n) dis[i] = rsqrtf((float)(cnt[i] + 1));   // +1 = self loop
}

// ---------------- exclusive scan (3 kernels) ----------------
__global__ void scan1_kernel(const int* __restrict__ cnt, int* __restrict__ off,
                             int* __restrict__ bsum, int n) {
    __shared__ int sh[256];
    int t = threadIdx.x;
    int base = blockIdx.x * SCAN_CHUNK + t * 8;
    int v[8];
    int run = 0;
    #pragma unroll
    for (int j = 0; j < 8; ++j) {
        int c = (base + j < n) ? cnt[base + j] : 0;
        v[j] = run; run += c;
    }
    sh[t] = run;
    __syncthreads();
    for (int o = 1; o < 256; o <<= 1) {
        int x = (t >= o) ? sh[t - o] : 0;
        __syncthreads();
        sh[t] += x;
        __syncthreads();
    }
    int prev = (t > 0) ? sh[t - 1] : 0;
    #pragma unroll
    for (int j = 0; j < 8; ++j)
        if (base + j < n) off[base + j] = prev + v[j];
    if (t == 255) bsum[blockIdx.x] = sh[255];
}

// single-wave shuffle scan (NB_SCAN=49 <= 64)
__global__ void scan2_kernel(int* bsum, int nb) {
    int lane = threadIdx.x;
    int orig = (lane < nb) ? bsum[lane] : 0;
    int v = orig;
    #pragma unroll
    for (int o = 1; o < 64; o <<= 1) {
        int t = __shfl_up(v, o);
        if (lane >= o) v += t;
    }
    if (lane < nb) bsum[lane] = v - orig;   // exclusive
}

__global__ void scan3_kernel(int* __restrict__ off, const int* __restrict__ bsum,
                             int n, int E) {
    int i = blockIdx.x * blockDim.x + threadIdx.x;
    if (i < n) {
        off[i] = off[i] + bsum[i / SCAN_CHUNK];
    } else if (i == n) {
        off[n] = E;
    }
}

// ---------------- bucketed CSR build ----------------
__global__ void binit_kernel(const int* __restrict__ off, int* __restrict__ bcur) {
    int b = blockIdx.x * 256 + threadIdx.x;
    if (b < NBUCK) bcur[b] = off[b << BSHIFT];
}

// Phase A: coarse scatter into bucket regions (dense runs per block)
__global__ void bucketA_kernel(const int* __restrict__ row, const int* __restrict__ col,
                               int* __restrict__ bcur, unsigned* __restrict__ tmp) {
    __shared__ int lcnt[NBUCK];
    __shared__ int lcur[NBUCK];
    int t = threadIdx.x;
    int e0 = (int)((long)blockIdx.x * N_EDGES / PA_BLOCKS);
    int e1 = (int)((long)(blockIdx.x + 1) * N_EDGES / PA_BLOCKS);
    for (int i = t; i < NBUCK; i += 256) lcnt[i] = 0;
    __syncthreads();
    for (int e = e0 + t; e < e1; e += 256)
        atomicAdd(&lcnt[col[e] >> BSHIFT], 1);
    __syncthreads();
    for (int b = t; b < NBUCK; b += 256) {
        int c = lcnt[b];
        lcur[b] = (c > 0) ? atomicAdd(&bcur[b], c) : 0;
    }
    __syncthreads();
    for (int e = e0 + t; e < e1; e += 256) {
        int cc = col[e];
        int b = cc >> BSHIFT;
        int p = atomicAdd(&lcur[b], 1);
        tmp[p] = ((unsigned)(cc & 127) << 17) | (unsigned)row[e];
    }
}

// Phase B: fine sort within each bucket region (L2-resident, dense writes)
__global__ void bucketB_kernel(const unsigned* __restrict__ tmp, const int* __restrict__ off,
                               int* __restrict__ srt) {
    __shared__ int lcur[128];
    int b = blockIdx.x;
    int t = threadIdx.x;
    int nb0 = b << BSHIFT;
    int hi = min(nb0 + 128, N_NODES);
    int base = off[nb0];
    if (t < 128) {
        int nn = nb0 + t;
        lcur[t] = (nn < hi) ? off[nn] - base : 0;
    }
    __syncthreads();
    int end = off[hi];
    for (int i = base + t; i < end; i += 256) {
        unsigned e = tmp[i];
        int c = (e >> 17) & 127;
        int r = (int)(e & 0x1FFFFu);
        int p = atomicAdd(&lcur[c], 1);
        srt[base + p] = r;
    }
}

// ---------------- W split-transpose setup ----------------
// wt1[ch][k] for ch<128, k<192 (k>=165 zero); wt2[ch][k] for ch<64, k<128
__global__ void wsplit_kernel(const float* __restrict__ W1, const float* __restrict__ W2,
                              ushort_t* __restrict__ wt1h, ushort_t* __restrict__ wt1l,
                              ushort_t* __restrict__ wt2h, ushort_t* __restrict__ wt2l) {
    int i = blockIdx.x * 256 + threadIdx.x;
    if (i < 128 * 192) {
        int ch = i / 192, k = i - ch * 192;
        float v = (k < IN_CH) ? W1[(size_t)k * 128 + ch] : 0.f;
        ushort_t h = f2bf(v);
        wt1h[i] = h;
        wt1l[i] = f2bf(v - bf2f(h));
    } else if (i < 128 * 192 + 64 * 128) {
        int j = i - 128 * 192;
        int ch = j / 128, k = j - ch * 128;
        float v = W2[(size_t)k * 64 + ch];
        ushort_t h = f2bf(v);
        wt2h[j] = h;
        wt2l[j] = f2bf(v - bf2f(h));
    }
}

// ---------------- MFMA GEMM: M[n][NOUT] = dis[n] * (X[n][KTOT] @ W[KTOT][NOUT]) ----
// split-bf16: x*w ~= xh*wh + xh*wl + xl*wh, fp32 accumulate, fp16 output.
// LDS rows padded to 40 ushorts (80B): frag-read bank-quads cycle all 8 -> 2-way only.
// 1-deep register pipeline: chunk c+1 global loads issued during chunk c MFMAs.
template<int NOUT, int KTOT, int KPAD>
__launch_bounds__(256)
__global__ void mfma_gemm_kernel(const float* __restrict__ X,
                                 const ushort_t* __restrict__ wth,
                                 const ushort_t* __restrict__ wtl,
                                 const float* __restrict__ dis,
                                 f16* __restrict__ M, int n_nodes) {
    constexpr int NCT = NOUT / 16;
    constexpr int NCHUNK = KPAD / 32;
    constexpr int XP = 40;               // padded row, ushorts (80B)
    constexpr int NW = (NOUT * 4 + 255) / 256;   // W frag loads per thread
    __shared__ ushort_t xsh[64][XP];
    __shared__ ushort_t xsl[64][XP];
    __shared__ ushort_t wsh[NOUT][XP];
    __shared__ ushort_t wsl[NOUT][XP];

    int t = threadIdx.x;
    int l = t & 63, wid = t >> 6;
    long node0 = (long)blockIdx.x * 64;

    int arow = wid * 16 + (l & 15);
    int kq = (l >> 4) * 8;

    f32x4 acc[NCT];
    #pragma unroll
    for (int ct = 0; ct < NCT; ++ct) acc[ct] = (f32x4){0.f, 0.f, 0.f, 0.f};

    // staging registers
    float xa[4], xb[4];
    bfrag8 wfh[NW], wfl[NW];

    auto loadX = [&](int c) {
        int k0 = c * 32;
        #pragma unroll
        for (int i = 0; i < 4; ++i) {
            int idx = t + i * 256;
            int node = idx >> 4, kp = idx & 15;
            long g = node0 + node;
            int k = k0 + 2 * kp;
            bool ok = (g < n_nodes);
            xa[i] = (ok && k < KTOT) ? X[g * KTOT + k] : 0.f;
            xb[i] = (ok && k + 1 < KTOT) ? X[g * KTOT + k + 1] : 0.f;
        }
    };
    auto loadW = [&](int c) {
        int k0 = c * 32;
        #pragma unroll
        for (int i = 0; i < NW; ++i) {
            int idx = t + i * 256;
            int ch = idx >> 2, q = idx & 3;
            wfh[i] = *(const bfrag8*)&wth[(size_t)ch * KPAD + k0 + q * 8];
            wfl[i] = *(const bfrag8*)&wtl[(size_t)ch * KPAD + k0 + q * 8];
        }
    };
    auto storeLDS = [&]() {
        #pragma unroll
        for (int i = 0; i < 4; ++i) {
            int idx = t + i * 256;
            int node = idx >> 4, kp = idx & 15;
            // truncation split for hi (exact prefix), RNE for lo
            ushort_t ha = (ushort_t)(__float_as_uint(xa[i]) >> 16);
            ushort_t la = f2bf(xa[i] - bf2f(ha));
            ushort_t hb = (ushort_t)(__float_as_uint(xb[i]) >> 16);
            ushort_t lb = f2bf(xb[i] - bf2f(hb));
            *(unsigned*)&xsh[node][2 * kp] = (unsigned)ha | ((unsigned)hb << 16);
            *(unsigned*)&xsl[node][2 * kp] = (unsigned)la | ((unsigned)lb << 16);
        }
        #pragma unroll
        for (int i = 0; i < NW; ++i) {
            int idx = t + i * 256;
            int ch = idx >> 2, q = idx & 3;
            *(bfrag8*)&wsh[ch][q * 8] = wfh[i];
            *(bfrag8*)&wsl[ch][q * 8] = wfl[i];
        }
    };

    loadX(0); loadW(0);
    for (int c = 0; c < NCHUNK; ++c) {
        storeLDS();
        __syncthreads();
        if (c + 1 < NCHUNK) { loadX(c + 1); loadW(c + 1); }
        bfrag8 ah = *(const bfrag8*)&xsh[arow][kq];
        bfrag8 al = *(const bfrag8*)&xsl[arow][kq];
        #pragma unroll
        for (int ct = 0; ct < NCT; ++ct) {
            bfrag8 bh = *(const bfrag8*)&wsh[ct * 16 + (l & 15)][kq];
            bfrag8 bl = *(const bfrag8*)&wsl[ct * 16 + (l & 15)][kq];
            acc[ct] = __builtin_amdgcn_mfma_f32_16x16x32_bf16(ah, bh, acc[ct], 0, 0, 0);
            acc[ct] = __builtin_amdgcn_mfma_f32_16x16x32_bf16(ah, bl, acc[ct], 0, 0, 0);
            acc[ct] = __builtin_amdgcn_mfma_f32_16x16x32_bf16(al, bh, acc[ct], 0, 0, 0);
        }
        __syncthreads();
    }

    int nl = wid * 16 + (l >> 4) * 4;
    float dv[4];
    #pragma unroll
    for (int j = 0; j < 4; ++j) {
        long node = node0 + nl + j;
        dv[j] = (node < n_nodes) ? dis[node] : 0.f;
    }
    #pragma unroll
    for (int ct = 0; ct < NCT; ++ct) {
        int ch = ct * 16 + (l & 15);
        #pragma unroll
        for (int j = 0; j < 4; ++j) {
            long node = node0 + nl + j;
            if (node < n_nodes)
                M[node * NOUT + ch] = (f16)(acc[ct][j] * dv[j]);
        }
    }
}

// ---------------- aggregation layer 1: 128 ch fp16, wave-per-node ----------------
// ms is pre-scaled by dis[src]; out = relu(dn * (ms[n] + sum ms[src]) + b1)
__global__ void agg1_kernel(const f16* __restrict__ ms, const int* __restrict__ srt,
                            const int* __restrict__ off, const float* __restrict__ dis,
                            const float* __restrict__ b1, float* __restrict__ h1) {
    int wave = threadIdx.x >> 6;
    int lane = threadIdx.x & 63;
    int n = blockIdx.x * 4 + wave;
    if (n >= N_NODES) return;
    float dn = dis[n];
    f16x2 a = ((const f16x2*)(ms + (size_t)n * 128))[lane];
    float accx = (float)a.x, accy = (float)a.y;
    int s0 = off[n], s1 = off[n + 1];
    for (int base = s0; base < s1; base += 64) {
        int sv = (base + lane < s1) ? srt[base + lane] : 0;
        int cnt = min(64, s1 - base);
        int j = 0;
        for (; j + 7 < cnt; j += 8) {
            f16x2 v0 = ((const f16x2*)(ms + (size_t)__builtin_amdgcn_readlane(sv, j + 0) * 128))[lane];
            f16x2 v1 = ((const f16x2*)(ms + (size_t)__builtin_amdgcn_readlane(sv, j + 1) * 128))[lane];
            f16x2 v2 = ((const f16x2*)(ms + (size_t)__builtin_amdgcn_readlane(sv, j + 2) * 128))[lane];
            f16x2 v3 = ((const f16x2*)(ms + (size_t)__builtin_amdgcn_readlane(sv, j + 3) * 128))[lane];
            f16x2 v4 = ((const f16x2*)(ms + (size_t)__builtin_amdgcn_readlane(sv, j + 4) * 128))[lane];
            f16x2 v5 = ((const f16x2*)(ms + (size_t)__builtin_amdgcn_readlane(sv, j + 5) * 128))[lane];
            f16x2 v6 = ((const f16x2*)(ms + (size_t)__builtin_amdgcn_readlane(sv, j + 6) * 128))[lane];
            f16x2 v7 = ((const f16x2*)(ms + (size_t)__builtin_amdgcn_readlane(sv, j + 7) * 128))[lane];
            accx += (float)v0.x + (float)v1.x + (float)v2.x + (float)v3.x
                  + (float)v4.x + (float)v5.x + (float)v6.x + (float)v7.x;
            accy += (float)v0.y + (float)v1.y + (float)v2.y + (float)v3.y
                  + (float)v4.y + (float)v5.y + (float)v6.y + (float)v7.y;
        }
        for (; j < cnt; ++j) {
            int s = __builtin_amdgcn_readlane(sv, j);
            f16x2 v = ((const f16x2*)(ms + (size_t)s * 128))[lane];
            accx += (float)v.x; accy += (float)v.y;
        }
    }
    float2 b = ((const float2*)b1)[lane];
    float rx = fmaxf(accx * dn + b.x, 0.f);
    float ry = fmaxf(accy * dn + b.y, 0.f);
    ((float2*)(h1 + (size_t)n * 128))[lane] = make_float2(rx, ry);
}

// ---------------- aggregation layer 2 (64 ch fp16) + output GEMM (64 -> 2) ----------------
__global__ void agg2_kernel(const f16* __restrict__ ms, const int* __restrict__ srt,
                            const int* __restrict__ off, const float* __restrict__ dis,
                            const float* __restrict__ b2, const float* __restrict__ Wo,
                            const float* __restrict__ bo, float* __restrict__ out) {
    int wave = threadIdx.x >> 6;
    int lane = threadIdx.x & 63;
    int n = blockIdx.x * 4 + wave;
    if (n >= N_NODES) return;
    float dn = dis[n];
    float acc = (float)ms[(size_t)n * 64 + lane];
    int s0 = off[n], s1 = off[n + 1];
    for (int base = s0; base < s1; base += 64) {
        int sv = (base + lane < s1) ? srt[base + lane] : 0;
        int cnt = min(64, s1 - base);
        int j = 0;
        for (; j + 7 < cnt; j += 8) {
            float v0 = (float)ms[(size_t)__builtin_amdgcn_readlane(sv, j + 0) * 64 + lane];
            float v1 = (float)ms[(size_t)__builtin_amdgcn_readlane(sv, j + 1) * 64 + lane];
            float v2 = (float)ms[(size_t)__builtin_amdgcn_readlane(sv, j + 2) * 64 + lane];
            float v3 = (float)ms[(size_t)__builtin_amdgcn_readlane(sv, j + 3) * 64 + lane];
            float v4 = (float)ms[(size_t)__builtin_amdgcn_readlane(sv, j + 4) * 64 + lane];
            float v5 = (float)ms[(size_t)__builtin_amdgcn_readlane(sv, j + 5) * 64 + lane];
            float v6 = (float)ms[(size_t)__builtin_amdgcn_readlane(sv, j + 6) * 64 + lane];
            float v7 = (float)ms[(size_t)__builtin_amdgcn_readlane(sv, j + 7) * 64 + lane];
            acc += v0 + v1 + v2 + v3 + v4 + v5 + v6 + v7;
        }
        for (; j < cnt; ++j) {
            acc += (float)ms[(size_t)__builtin_amdgcn_readlane(sv, j) * 64 + lane];
        }
    }
    float v = fmaxf(acc * dn + b2[lane], 0.f);
    float p0 = v * Wo[lane * 2];
    float p1 = v * Wo[lane * 2 + 1];
    #pragma unroll
    for (int o = 32; o > 0; o >>= 1) {
        p0 += __shfl_xor(p0, o);
        p1 += __shfl_xor(p1, o);
    }
    if (lane == 0) {
        out[(size_t)n * 2]     = p0 + bo[0];
        out[(size_t)n * 2 + 1] = p1 + bo[1];
    }
}

// ---------------- launch ----------------
extern "C" void kernel_launch(void* const* d_in, const int* in_sizes, int n_in,
                              void* d_out, int out_size, void* d_ws, size_t ws_size,
                              hipStream_t stream) {
    const float* x  = (const float*)d_in[0];
    const int*   ei = (const int*)d_in[1];
    const int*   row = ei;
    const int*   col = ei + N_EDGES;
    const float* W1 = (const float*)d_in[2];
    const float* b1 = (const float*)d_in[3];
    const float* W2 = (const float*)d_in[4];
    const float* b2 = (const float*)d_in[5];
    const float* Wo = (const float*)d_in[6];
    const float* bo = (const float*)d_in[7];
    float* out = (float*)d_out;

    char* base = (char*)d_ws;
    auto alloc = [&](size_t bytes) {
        char* p = base;
        base += (bytes + 255) & ~(size_t)255;
        return p;
    };
    int*      cnt  = (int*)alloc((size_t)N_NODES * 4);
    int*      off  = (int*)alloc((size_t)(N_NODES + 1) * 4);
    float*    dis  = (float*)alloc((size_t)N_NODES * 4);
    int*      bsum = (int*)alloc(256);
    int*      bcur = (int*)alloc((size_t)NBUCK * 4);
    unsigned* tmp  = (unsigned*)alloc((size_t)N_EDGES * 4);
    int*      srt  = (int*)alloc((size_t)N_EDGES * 4);
    f16*      m    = (f16*)alloc((size_t)N_NODES * 128 * 2);   // m1, reused as m2
    float*    h1   = (float*)alloc((size_t)N_NODES * 128 * 4);
    ushort_t* wt1h = (ushort_t*)alloc((size_t)128 * 192 * 2);
    ushort_t* wt1l = (ushort_t*)alloc((size_t)128 * 192 * 2);
    ushort_t* wt2h = (ushort_t*)alloc((size_t)64 * 128 * 2);
    ushort_t* wt2l = (ushort_t*)alloc((size_t)64 * 128 * 2);

    hipMemsetAsync(cnt, 0, (size_t)N_NODES * 4, stream);
    count_kernel<<<1024, 256, 0, stream>>>(col, cnt, N_EDGES);
    dis_kernel<<<(N_NODES + 255) / 256, 256, 0, stream>>>(cnt, dis, N_NODES);
    scan1_kernel<<<NB_SCAN, 256, 0, stream>>>(cnt, off, bsum, N_NODES);
    scan2_kernel<<<1, 64, 0, stream>>>(bsum, NB_SCAN);
    scan3_kernel<<<(N_NODES + 256) / 256, 256, 0, stream>>>(off, bsum, N_NODES, N_EDGES);
    binit_kernel<<<(NBUCK + 255) / 256, 256, 0, stream>>>(off, bcur);
    bucketA_kernel<<<PA_BLOCKS, 256, 0, stream>>>(row, col, bcur, tmp);
    bucketB_kernel<<<NBUCK, 256, 0, stream>>>(tmp, off, srt);
    wsplit_kernel<<<(128 * 192 + 64 * 128 + 255) / 256, 256, 0, stream>>>(W1, W2, wt1h, wt1l, wt2h, wt2l);

    // layer 1: m = dis * (x @ W1)  [MFMA split-bf16 -> fp16]
    mfma_gemm_kernel<128, 165, 192><<<(N_NODES + 63) / 64, 256, 0, stream>>>(x, wt1h, wt1l, dis, m, N_NODES);
    agg1_kernel<<<(N_NODES + 3) / 4, 256, 0, stream>>>(m, srt, off, dis, b1, h1);

    // layer 2: m = dis * (h1 @ W2)  [MFMA split-bf16 -> fp16]
    mfma_gemm_kernel<64, 128, 128><<<(N_NODES + 63) / 64, 256, 0, stream>>>(h1, wt2h, wt2l, dis, m, N_NODES);
    agg2_kernel<<<(N_NODES + 3) / 4, 256, 0, stream>>>(m, srt, off, dis, b2, Wo, bo, out);
}

// Round 9
// 240.268 us; speedup vs baseline: 2.4729x; 1.2922x over previous
//
#include <hip/hip_runtime.h>

#define N_NODES 100000
#define N_EDGES 1600000
#define IN_CH   165
#define SCAN_CHUNK 2048   // 256 threads * 8 elems
#define NB_SCAN ((N_NODES + SCAN_CHUNK - 1) / SCAN_CHUNK)
#define BSHIFT 7
#define NBUCK  ((N_NODES + 127) / 128)   // 782
#define BCAP   3072                       // bucket region capacity (mean 2046, 11+ sigma)
#define PA_BLOCKS 196

typedef unsigned short ushort_t;
typedef _Float16 f16;
typedef _Float16 f16x2 __attribute__((ext_vector_type(2)));
typedef short bfrag8 __attribute__((ext_vector_type(8)));   // 8 bf16 (4 VGPRs)
typedef float f32x4 __attribute__((ext_vector_type(4)));

// bf16 round-to-nearest-even
__device__ __forceinline__ ushort_t f2bf(float f) {
    unsigned u = __float_as_uint(f);
    unsigned r = (u + 0x7fffu + ((u >> 16) & 1u)) >> 16;
    return (ushort_t)r;
}
__device__ __forceinline__ float bf2f(ushort_t h) {
    return __uint_as_float(((unsigned)h) << 16);
}

// ---------------- exclusive scan over cnt (3 kernels) ----------------
__global__ void scan1_kernel(const int* __restrict__ cnt, int* __restrict__ off,
                             int* __restrict__ bsum, int n) {
    __shared__ int sh[256];
    int t = threadIdx.x;
    int base = blockIdx.x * SCAN_CHUNK + t * 8;
    int v[8];
    int run = 0;
    #pragma unroll
    for (int j = 0; j < 8; ++j) {
        int c = (base + j < n) ? cnt[base + j] : 0;
        v[j] = run; run += c;
    }
    sh[t] = run;
    __syncthreads();
    for (int o = 1; o < 256; o <<= 1) {
        int x = (t >= o) ? sh[t - o] : 0;
        __syncthreads();
        sh[t] += x;
        __syncthreads();
    }
    int prev = (t > 0) ? sh[t - 1] : 0;
    #pragma unroll
    for (int j = 0; j < 8; ++j)
        if (base + j < n) off[base + j] = prev + v[j];
    if (t == 255) bsum[blockIdx.x] = sh[255];
}

// single-wave shuffle scan (NB_SCAN=49 <= 64)
__global__ void scan2_kernel(int* bsum, int nb) {
    int lane = threadIdx.x;
    int orig = (lane < nb) ? bsum[lane] : 0;
    int v = orig;
    #pragma unroll
    for (int o = 1; o < 64; o <<= 1) {
        int t = __shfl_up(v, o);
        if (lane >= o) v += t;
    }
    if (lane < nb) bsum[lane] = v - orig;   // exclusive
}

__global__ void scan3_kernel(int* __restrict__ off, const int* __restrict__ bsum,
                             int n, int E) {
    int i = blockIdx.x * blockDim.x + threadIdx.x;
    if (i < n) {
        off[i] = off[i] + bsum[i / SCAN_CHUNK];
    } else if (i == n) {
        off[n] = E;
    }
}

// ---------------- bucketed CSR build (fixed-capacity regions, no pre-count) ----
// Phase A: coarse scatter into fixed bucket regions tmp[b*BCAP ...]
__global__ void bucketA_kernel(const int* __restrict__ row, const int* __restrict__ col,
                               int* __restrict__ bfill, unsigned* __restrict__ tmp) {
    __shared__ int lcnt[NBUCK];
    __shared__ int lcur[NBUCK];
    int t = threadIdx.x;
    int e0 = (int)((long)blockIdx.x * N_EDGES / PA_BLOCKS);
    int e1 = (int)((long)(blockIdx.x + 1) * N_EDGES / PA_BLOCKS);
    for (int i = t; i < NBUCK; i += 256) lcnt[i] = 0;
    __syncthreads();
    for (int e = e0 + t; e < e1; e += 256)
        atomicAdd(&lcnt[col[e] >> BSHIFT], 1);
    __syncthreads();
    for (int b = t; b < NBUCK; b += 256) {
        int c = lcnt[b];
        lcur[b] = (c > 0) ? (b * BCAP + atomicAdd(&bfill[b], c)) : 0;
    }
    __syncthreads();
    for (int e = e0 + t; e < e1; e += 256) {
        int cc = col[e];
        int b = cc >> BSHIFT;
        int p = atomicAdd(&lcur[b], 1);
        tmp[p] = ((unsigned)(cc & 127) << 17) | (unsigned)row[e];
    }
}

// countB: per-bucket per-node degree from tmp -> cnt + dis (no global atomics)
__global__ void countB_kernel(const unsigned* __restrict__ tmp, const int* __restrict__ bfill,
                              int* __restrict__ cnt, float* __restrict__ dis) {
    __shared__ int lcnt[128];
    int b = blockIdx.x, t = threadIdx.x;
    if (t < 128) lcnt[t] = 0;
    __syncthreads();
    int total = min(bfill[b], BCAP);
    const unsigned* reg = tmp + (size_t)b * BCAP;
    for (int i = t; i < total; i += 256)
        atomicAdd(&lcnt[(reg[i] >> 17) & 127], 1);
    __syncthreads();
    if (t < 128) {
        int n = (b << BSHIFT) + t;
        if (n < N_NODES) {
            int c = lcnt[t];
            cnt[n] = c;
            dis[n] = rsqrtf((float)(c + 1));   // +1 = self loop
        }
    }
}

// Phase B: fine sort within each bucket region (L2-resident, dense writes)
__global__ void bucketB_kernel(const unsigned* __restrict__ tmp, const int* __restrict__ bfill,
                               const int* __restrict__ off, int* __restrict__ srt) {
    __shared__ int lcur[128];
    int b = blockIdx.x;
    int t = threadIdx.x;
    int nb0 = b << BSHIFT;
    int hi = min(nb0 + 128, N_NODES);
    int base = off[nb0];
    if (t < 128) {
        int nn = nb0 + t;
        lcur[t] = (nn < hi) ? off[nn] - base : 0;
    }
    __syncthreads();
    int total = min(bfill[b], BCAP);
    const unsigned* reg = tmp + (size_t)b * BCAP;
    for (int i = t; i < total; i += 256) {
        unsigned e = reg[i];
        int c = (e >> 17) & 127;
        int r = (int)(e & 0x1FFFFu);
        int p = atomicAdd(&lcur[c], 1);
        srt[base + p] = r;
    }
}

// ---------------- W split-transpose setup ----------------
// wt1[ch][k] for ch<128, k<192 (k>=165 zero); wt2[ch][k] for ch<64, k<128
__global__ void wsplit_kernel(const float* __restrict__ W1, const float* __restrict__ W2,
                              ushort_t* __restrict__ wt1h, ushort_t* __restrict__ wt1l,
                              ushort_t* __restrict__ wt2h, ushort_t* __restrict__ wt2l) {
    int i = blockIdx.x * 256 + threadIdx.x;
    if (i < 128 * 192) {
        int ch = i / 192, k = i - ch * 192;
        float v = (k < IN_CH) ? W1[(size_t)k * 128 + ch] : 0.f;
        ushort_t h = f2bf(v);
        wt1h[i] = h;
        wt1l[i] = f2bf(v - bf2f(h));
    } else if (i < 128 * 192 + 64 * 128) {
        int j = i - 128 * 192;
        int ch = j / 128, k = j - ch * 128;
        float v = W2[(size_t)k * 64 + ch];
        ushort_t h = f2bf(v);
        wt2h[j] = h;
        wt2l[j] = f2bf(v - bf2f(h));
    }
}

// ---------------- MFMA GEMM: M[n][NOUT] = dis[n] * (X[n][KTOT] @ W[KTOT][NOUT]) ----
// split-bf16: x*w ~= xh*wh + xh*wl + xl*wh, fp32 accumulate, fp16 output.
// LDS rows padded to 40 ushorts (80B): frag-read bank-quads cycle all 8 -> 2-way only.
// 1-deep register pipeline: chunk c+1 global loads issued during chunk c MFMAs.
template<int NOUT, int KTOT, int KPAD>
__launch_bounds__(256)
__global__ void mfma_gemm_kernel(const float* __restrict__ X,
                                 const ushort_t* __restrict__ wth,
                                 const ushort_t* __restrict__ wtl,
                                 const float* __restrict__ dis,
                                 f16* __restrict__ M, int n_nodes) {
    constexpr int NCT = NOUT / 16;
    constexpr int NCHUNK = KPAD / 32;
    constexpr int XP = 40;               // padded row, ushorts (80B)
    constexpr int NW = (NOUT * 4 + 255) / 256;   // W frag loads per thread
    __shared__ ushort_t xsh[64][XP];
    __shared__ ushort_t xsl[64][XP];
    __shared__ ushort_t wsh[NOUT][XP];
    __shared__ ushort_t wsl[NOUT][XP];

    int t = threadIdx.x;
    int l = t & 63, wid = t >> 6;
    long node0 = (long)blockIdx.x * 64;

    int arow = wid * 16 + (l & 15);
    int kq = (l >> 4) * 8;

    f32x4 acc[NCT];
    #pragma unroll
    for (int ct = 0; ct < NCT; ++ct) acc[ct] = (f32x4){0.f, 0.f, 0.f, 0.f};

    // staging registers
    float xa[4], xb[4];
    bfrag8 wfh[NW], wfl[NW];

    auto loadX = [&](int c) {
        int k0 = c * 32;
        #pragma unroll
        for (int i = 0; i < 4; ++i) {
            int idx = t + i * 256;
            int node = idx >> 4, kp = idx & 15;
            long g = node0 + node;
            int k = k0 + 2 * kp;
            bool ok = (g < n_nodes);
            xa[i] = (ok && k < KTOT) ? X[g * KTOT + k] : 0.f;
            xb[i] = (ok && k + 1 < KTOT) ? X[g * KTOT + k + 1] : 0.f;
        }
    };
    auto loadW = [&](int c) {
        int k0 = c * 32;
        #pragma unroll
        for (int i = 0; i < NW; ++i) {
            int idx = t + i * 256;
            int ch = idx >> 2, q = idx & 3;
            wfh[i] = *(const bfrag8*)&wth[(size_t)ch * KPAD + k0 + q * 8];
            wfl[i] = *(const bfrag8*)&wtl[(size_t)ch * KPAD + k0 + q * 8];
        }
    };
    auto storeLDS = [&]() {
        #pragma unroll
        for (int i = 0; i < 4; ++i) {
            int idx = t + i * 256;
            int node = idx >> 4, kp = idx & 15;
            // truncation split for hi (exact prefix), RNE for lo
            ushort_t ha = (ushort_t)(__float_as_uint(xa[i]) >> 16);
            ushort_t la = f2bf(xa[i] - bf2f(ha));
            ushort_t hb = (ushort_t)(__float_as_uint(xb[i]) >> 16);
            ushort_t lb = f2bf(xb[i] - bf2f(hb));
            *(unsigned*)&xsh[node][2 * kp] = (unsigned)ha | ((unsigned)hb << 16);
            *(unsigned*)&xsl[node][2 * kp] = (unsigned)la | ((unsigned)lb << 16);
        }
        #pragma unroll
        for (int i = 0; i < NW; ++i) {
            int idx = t + i * 256;
            int ch = idx >> 2, q = idx & 3;
            *(bfrag8*)&wsh[ch][q * 8] = wfh[i];
            *(bfrag8*)&wsl[ch][q * 8] = wfl[i];
        }
    };

    loadX(0); loadW(0);
    for (int c = 0; c < NCHUNK; ++c) {
        storeLDS();
        __syncthreads();
        if (c + 1 < NCHUNK) { loadX(c + 1); loadW(c + 1); }
        bfrag8 ah = *(const bfrag8*)&xsh[arow][kq];
        bfrag8 al = *(const bfrag8*)&xsl[arow][kq];
        #pragma unroll
        for (int ct = 0; ct < NCT; ++ct) {
            bfrag8 bh = *(const bfrag8*)&wsh[ct * 16 + (l & 15)][kq];
            bfrag8 bl = *(const bfrag8*)&wsl[ct * 16 + (l & 15)][kq];
            acc[ct] = __builtin_amdgcn_mfma_f32_16x16x32_bf16(ah, bh, acc[ct], 0, 0, 0);
            acc[ct] = __builtin_amdgcn_mfma_f32_16x16x32_bf16(ah, bl, acc[ct], 0, 0, 0);
            acc[ct] = __builtin_amdgcn_mfma_f32_16x16x32_bf16(al, bh, acc[ct], 0, 0, 0);
        }
        __syncthreads();
    }

    int nl = wid * 16 + (l >> 4) * 4;
    float dv[4];
    #pragma unroll
    for (int j = 0; j < 4; ++j) {
        long node = node0 + nl + j;
        dv[j] = (node < n_nodes) ? dis[node] : 0.f;
    }
    #pragma unroll
    for (int ct = 0; ct < NCT; ++ct) {
        int ch = ct * 16 + (l & 15);
        #pragma unroll
        for (int j = 0; j < 4; ++j) {
            long node = node0 + nl + j;
            if (node < n_nodes)
                M[node * NOUT + ch] = (f16)(acc[ct][j] * dv[j]);
        }
    }
}

// ---------------- aggregation layer 1: 128 ch fp16, wave-per-node ----------------
// ms is pre-scaled by dis[src]; out = relu(dn * (ms[n] + sum ms[src]) + b1)
// 16-deep gather unroll + next-batch srt prefetch for MLP.
__global__ void agg1_kernel(const f16* __restrict__ ms, const int* __restrict__ srt,
                            const int* __restrict__ off, const float* __restrict__ dis,
                            const float* __restrict__ b1, float* __restrict__ h1) {
    int wave = threadIdx.x >> 6;
    int lane = threadIdx.x & 63;
    int n = blockIdx.x * 4 + wave;
    if (n >= N_NODES) return;
    float dn = dis[n];
    f16x2 a = ((const f16x2*)(ms + (size_t)n * 128))[lane];
    float accx = (float)a.x, accy = (float)a.y;
    int s0 = off[n], s1 = off[n + 1];
    int sv = (s0 + lane < s1) ? srt[s0 + lane] : 0;
    for (int base = s0; base < s1; base += 64) {
        int nb2 = base + 64;
        int svn = (nb2 + lane < s1) ? srt[nb2 + lane] : 0;
        int cnt = min(64, s1 - base);
        int j = 0;
        for (; j + 15 < cnt; j += 16) {
            f16x2 v[16];
            #pragma unroll
            for (int u = 0; u < 16; ++u)
                v[u] = ((const f16x2*)(ms + (size_t)__builtin_amdgcn_readlane(sv, j + u) * 128))[lane];
            #pragma unroll
            for (int u = 0; u < 16; ++u) { accx += (float)v[u].x; accy += (float)v[u].y; }
        }
        for (; j + 3 < cnt; j += 4) {
            f16x2 v[4];
            #pragma unroll
            for (int u = 0; u < 4; ++u)
                v[u] = ((const f16x2*)(ms + (size_t)__builtin_amdgcn_readlane(sv, j + u) * 128))[lane];
            #pragma unroll
            for (int u = 0; u < 4; ++u) { accx += (float)v[u].x; accy += (float)v[u].y; }
        }
        for (; j < cnt; ++j) {
            f16x2 v = ((const f16x2*)(ms + (size_t)__builtin_amdgcn_readlane(sv, j) * 128))[lane];
            accx += (float)v.x; accy += (float)v.y;
        }
        sv = svn;
    }
    float2 b = ((const float2*)b1)[lane];
    float rx = fmaxf(accx * dn + b.x, 0.f);
    float ry = fmaxf(accy * dn + b.y, 0.f);
    ((float2*)(h1 + (size_t)n * 128))[lane] = make_float2(rx, ry);
}

// ---------------- aggregation layer 2 (64 ch fp16) + output GEMM (64 -> 2) ----------------
__global__ void agg2_kernel(const f16* __restrict__ ms, const int* __restrict__ srt,
                            const int* __restrict__ off, const float* __restrict__ dis,
                            const float* __restrict__ b2, const float* __restrict__ Wo,
                            const float* __restrict__ bo, float* __restrict__ out) {
    int wave = threadIdx.x >> 6;
    int lane = threadIdx.x & 63;
    int n = blockIdx.x * 4 + wave;
    if (n >= N_NODES) return;
    float dn = dis[n];
    float acc = (float)ms[(size_t)n * 64 + lane];
    int s0 = off[n], s1 = off[n + 1];
    int sv = (s0 + lane < s1) ? srt[s0 + lane] : 0;
    for (int base = s0; base < s1; base += 64) {
        int nb2 = base + 64;
        int svn = (nb2 + lane < s1) ? srt[nb2 + lane] : 0;
        int cnt = min(64, s1 - base);
        int j = 0;
        for (; j + 15 < cnt; j += 16) {
            f16 v[16];
            #pragma unroll
            for (int u = 0; u < 16; ++u)
                v[u] = ms[(size_t)__builtin_amdgcn_readlane(sv, j + u) * 64 + lane];
            #pragma unroll
            for (int u = 0; u < 16; ++u) acc += (float)v[u];
        }
        for (; j + 3 < cnt; j += 4) {
            f16 v[4];
            #pragma unroll
            for (int u = 0; u < 4; ++u)
                v[u] = ms[(size_t)__builtin_amdgcn_readlane(sv, j + u) * 64 + lane];
            #pragma unroll
            for (int u = 0; u < 4; ++u) acc += (float)v[u];
        }
        for (; j < cnt; ++j)
            acc += (float)ms[(size_t)__builtin_amdgcn_readlane(sv, j) * 64 + lane];
        sv = svn;
    }
    float v = fmaxf(acc * dn + b2[lane], 0.f);
    float p0 = v * Wo[lane * 2];
    float p1 = v * Wo[lane * 2 + 1];
    #pragma unroll
    for (int o = 32; o > 0; o >>= 1) {
        p0 += __shfl_xor(p0, o);
        p1 += __shfl_xor(p1, o);
    }
    if (lane == 0) {
        out[(size_t)n * 2]     = p0 + bo[0];
        out[(size_t)n * 2 + 1] = p1 + bo[1];
    }
}

// ---------------- launch ----------------
extern "C" void kernel_launch(void* const* d_in, const int* in_sizes, int n_in,
                              void* d_out, int out_size, void* d_ws, size_t ws_size,
                              hipStream_t stream) {
    const float* x  = (const float*)d_in[0];
    const int*   ei = (const int*)d_in[1];
    const int*   row = ei;
    const int*   col = ei + N_EDGES;
    const float* W1 = (const float*)d_in[2];
    const float* b1 = (const float*)d_in[3];
    const float* W2 = (const float*)d_in[4];
    const float* b2 = (const float*)d_in[5];
    const float* Wo = (const float*)d_in[6];
    const float* bo = (const float*)d_in[7];
    float* out = (float*)d_out;

    char* base = (char*)d_ws;
    auto alloc = [&](size_t bytes) {
        char* p = base;
        base += (bytes + 255) & ~(size_t)255;
        return p;
    };
    int*      cnt  = (int*)alloc((size_t)N_NODES * 4);
    int*      off  = (int*)alloc((size_t)(N_NODES + 1) * 4);
    float*    dis  = (float*)alloc((size_t)N_NODES * 4);
    int*      bsum = (int*)alloc(256);
    int*      bfill= (int*)alloc((size_t)NBUCK * 4);
    unsigned* tmp  = (unsigned*)alloc((size_t)NBUCK * BCAP * 4 + 4096);
    int*      srt  = (int*)alloc((size_t)N_EDGES * 4);
    f16*      m    = (f16*)alloc((size_t)N_NODES * 128 * 2);   // m1, reused as m2
    float*    h1   = (float*)alloc((size_t)N_NODES * 128 * 4);
    ushort_t* wt1h = (ushort_t*)alloc((size_t)128 * 192 * 2);
    ushort_t* wt1l = (ushort_t*)alloc((size_t)128 * 192 * 2);
    ushort_t* wt2h = (ushort_t*)alloc((size_t)64 * 128 * 2);
    ushort_t* wt2l = (ushort_t*)alloc((size_t)64 * 128 * 2);

    hipMemsetAsync(bfill, 0, (size_t)NBUCK * 4, stream);
    bucketA_kernel<<<PA_BLOCKS, 256, 0, stream>>>(row, col, bfill, tmp);
    countB_kernel<<<NBUCK, 256, 0, stream>>>(tmp, bfill, cnt, dis);
    scan1_kernel<<<NB_SCAN, 256, 0, stream>>>(cnt, off, bsum, N_NODES);
    scan2_kernel<<<1, 64, 0, stream>>>(bsum, NB_SCAN);
    scan3_kernel<<<(N_NODES + 256) / 256, 256, 0, stream>>>(off, bsum, N_NODES, N_EDGES);
    bucketB_kernel<<<NBUCK, 256, 0, stream>>>(tmp, bfill, off, srt);
    wsplit_kernel<<<(128 * 192 + 64 * 128 + 255) / 256, 256, 0, stream>>>(W1, W2, wt1h, wt1l, wt2h, wt2l);

    // layer 1: m = dis * (x @ W1)  [MFMA split-bf16 -> fp16]
    mfma_gemm_kernel<128, 165, 192><<<(N_NODES + 63) / 64, 256, 0, stream>>>(x, wt1h, wt1l, dis, m, N_NODES);
    agg1_kernel<<<(N_NODES + 3) / 4, 256, 0, stream>>>(m, srt, off, dis, b1, h1);

    // layer 2: m = dis * (h1 @ W2)  [MFMA split-bf16 -> fp16]
    mfma_gemm_kernel<64, 128, 128><<<(N_NODES + 63) / 64, 256, 0, stream>>>(h1, wt2h, wt2l, dis, m, N_NODES);
    agg2_kernel<<<(N_NODES + 3) / 4, 256, 0, stream>>>(m, srt, off, dis, b2, Wo, bo, out);
}

// Round 10
// 238.905 us; speedup vs baseline: 2.4870x; 1.0057x over previous
//
#include <hip/hip_runtime.h>

#define N_NODES 100000
#define N_EDGES 1600000
#define IN_CH   165
#define SCAN_CHUNK 2048   // 256 threads * 8 elems
#define NB_SCAN ((N_NODES + SCAN_CHUNK - 1) / SCAN_CHUNK)
#define BSHIFT 7
#define NBUCK  ((N_NODES + 127) / 128)   // 782
#define BCAP   3072                       // bucket region capacity (mean 2046, 11+ sigma)
#define PA_BLOCKS 196

typedef unsigned short ushort_t;
typedef _Float16 f16;
typedef _Float16 f16x2 __attribute__((ext_vector_type(2)));
typedef _Float16 f16x8 __attribute__((ext_vector_type(8)));
typedef short bfrag8 __attribute__((ext_vector_type(8)));   // 8 bf16 (4 VGPRs)
typedef float f32x4 __attribute__((ext_vector_type(4)));

// bf16 round-to-nearest-even
__device__ __forceinline__ ushort_t f2bf(float f) {
    unsigned u = __float_as_uint(f);
    unsigned r = (u + 0x7fffu + ((u >> 16) & 1u)) >> 16;
    return (ushort_t)r;
}
__device__ __forceinline__ float bf2f(ushort_t h) {
    return __uint_as_float(((unsigned)h) << 16);
}

// ---------------- exclusive scan over cnt (3 kernels) ----------------
__global__ void scan1_kernel(const int* __restrict__ cnt, int* __restrict__ off,
                             int* __restrict__ bsum, int n) {
    __shared__ int sh[256];
    int t = threadIdx.x;
    int base = blockIdx.x * SCAN_CHUNK + t * 8;
    int v[8];
    int run = 0;
    #pragma unroll
    for (int j = 0; j < 8; ++j) {
        int c = (base + j < n) ? cnt[base + j] : 0;
        v[j] = run; run += c;
    }
    sh[t] = run;
    __syncthreads();
    for (int o = 1; o < 256; o <<= 1) {
        int x = (t >= o) ? sh[t - o] : 0;
        __syncthreads();
        sh[t] += x;
        __syncthreads();
    }
    int prev = (t > 0) ? sh[t - 1] : 0;
    #pragma unroll
    for (int j = 0; j < 8; ++j)
        if (base + j < n) off[base + j] = prev + v[j];
    if (t == 255) bsum[blockIdx.x] = sh[255];
}

// single-wave shuffle scan (NB_SCAN=49 <= 64)
__global__ void scan2_kernel(int* bsum, int nb) {
    int lane = threadIdx.x;
    int orig = (lane < nb) ? bsum[lane] : 0;
    int v = orig;
    #pragma unroll
    for (int o = 1; o < 64; o <<= 1) {
        int t = __shfl_up(v, o);
        if (lane >= o) v += t;
    }
    if (lane < nb) bsum[lane] = v - orig;   // exclusive
}

__global__ void scan3_kernel(int* __restrict__ off, const int* __restrict__ bsum,
                             int n, int E) {
    int i = blockIdx.x * blockDim.x + threadIdx.x;
    if (i < n) {
        off[i] = off[i] + bsum[i / SCAN_CHUNK];
    } else if (i == n) {
        off[n] = E;
    }
}

// ---------------- bucketed CSR build (fixed-capacity regions, no pre-count) ----
__global__ void bucketA_kernel(const int* __restrict__ row, const int* __restrict__ col,
                               int* __restrict__ bfill, unsigned* __restrict__ tmp) {
    __shared__ int lcnt[NBUCK];
    __shared__ int lcur[NBUCK];
    int t = threadIdx.x;
    int e0 = (int)((long)blockIdx.x * N_EDGES / PA_BLOCKS);
    int e1 = (int)((long)(blockIdx.x + 1) * N_EDGES / PA_BLOCKS);
    for (int i = t; i < NBUCK; i += 256) lcnt[i] = 0;
    __syncthreads();
    for (int e = e0 + t; e < e1; e += 256)
        atomicAdd(&lcnt[col[e] >> BSHIFT], 1);
    __syncthreads();
    for (int b = t; b < NBUCK; b += 256) {
        int c = lcnt[b];
        lcur[b] = (c > 0) ? (b * BCAP + atomicAdd(&bfill[b], c)) : 0;
    }
    __syncthreads();
    for (int e = e0 + t; e < e1; e += 256) {
        int cc = col[e];
        int b = cc >> BSHIFT;
        int p = atomicAdd(&lcur[b], 1);
        tmp[p] = ((unsigned)(cc & 127) << 17) | (unsigned)row[e];
    }
}

// countB: per-bucket per-node degree from tmp -> cnt + dis (no global atomics)
__global__ void countB_kernel(const unsigned* __restrict__ tmp, const int* __restrict__ bfill,
                              int* __restrict__ cnt, float* __restrict__ dis) {
    __shared__ int lcnt[128];
    int b = blockIdx.x, t = threadIdx.x;
    if (t < 128) lcnt[t] = 0;
    __syncthreads();
    int total = min(bfill[b], BCAP);
    const unsigned* reg = tmp + (size_t)b * BCAP;
    for (int i = t; i < total; i += 256)
        atomicAdd(&lcnt[(reg[i] >> 17) & 127], 1);
    __syncthreads();
    if (t < 128) {
        int n = (b << BSHIFT) + t;
        if (n < N_NODES) {
            int c = lcnt[t];
            cnt[n] = c;
            dis[n] = rsqrtf((float)(c + 1));   // +1 = self loop
        }
    }
}

// Phase B: fine sort within each bucket region (L2-resident, dense writes)
__global__ void bucketB_kernel(const unsigned* __restrict__ tmp, const int* __restrict__ bfill,
                               const int* __restrict__ off, int* __restrict__ srt) {
    __shared__ int lcur[128];
    int b = blockIdx.x;
    int t = threadIdx.x;
    int nb0 = b << BSHIFT;
    int hi = min(nb0 + 128, N_NODES);
    int base = off[nb0];
    if (t < 128) {
        int nn = nb0 + t;
        lcur[t] = (nn < hi) ? off[nn] - base : 0;
    }
    __syncthreads();
    int total = min(bfill[b], BCAP);
    const unsigned* reg = tmp + (size_t)b * BCAP;
    for (int i = t; i < total; i += 256) {
        unsigned e = reg[i];
        int c = (e >> 17) & 127;
        int r = (int)(e & 0x1FFFFu);
        int p = atomicAdd(&lcur[c], 1);
        srt[base + p] = r;
    }
}

// ---------------- W split-transpose setup ----------------
__global__ void wsplit_kernel(const float* __restrict__ W1, const float* __restrict__ W2,
                              ushort_t* __restrict__ wt1h, ushort_t* __restrict__ wt1l,
                              ushort_t* __restrict__ wt2h, ushort_t* __restrict__ wt2l) {
    int i = blockIdx.x * 256 + threadIdx.x;
    if (i < 128 * 192) {
        int ch = i / 192, k = i - ch * 192;
        float v = (k < IN_CH) ? W1[(size_t)k * 128 + ch] : 0.f;
        ushort_t h = f2bf(v);
        wt1h[i] = h;
        wt1l[i] = f2bf(v - bf2f(h));
    } else if (i < 128 * 192 + 64 * 128) {
        int j = i - 128 * 192;
        int ch = j / 128, k = j - ch * 128;
        float v = W2[(size_t)k * 64 + ch];
        ushort_t h = f2bf(v);
        wt2h[j] = h;
        wt2l[j] = f2bf(v - bf2f(h));
    }
}

// ---------------- MFMA GEMM: M[n][NOUT] = dis[n] * (X[n][KTOT] @ W[KTOT][NOUT]) ----
// split-bf16: x*w ~= xh*wh + xh*wl + xl*wh, fp32 accumulate, fp16 output.
// F16IN: X is fp16 (exact bf16 hi/lo re-split). LDS rows padded to 40 ushorts.
template<int NOUT, int KTOT, int KPAD, bool F16IN>
__launch_bounds__(256)
__global__ void mfma_gemm_kernel(const void* __restrict__ Xv,
                                 const ushort_t* __restrict__ wth,
                                 const ushort_t* __restrict__ wtl,
                                 const float* __restrict__ dis,
                                 f16* __restrict__ M, int n_nodes) {
    constexpr int NCT = NOUT / 16;
    constexpr int NCHUNK = KPAD / 32;
    constexpr int XP = 40;               // padded row, ushorts (80B)
    constexpr int NW = (NOUT * 4 + 255) / 256;   // W frag loads per thread
    __shared__ ushort_t xsh[64][XP];
    __shared__ ushort_t xsl[64][XP];
    __shared__ ushort_t wsh[NOUT][XP];
    __shared__ ushort_t wsl[NOUT][XP];

    int t = threadIdx.x;
    int l = t & 63, wid = t >> 6;
    long node0 = (long)blockIdx.x * 64;

    int arow = wid * 16 + (l & 15);
    int kq = (l >> 4) * 8;

    f32x4 acc[NCT];
    #pragma unroll
    for (int ct = 0; ct < NCT; ++ct) acc[ct] = (f32x4){0.f, 0.f, 0.f, 0.f};

    float xa[4], xb[4];
    bfrag8 wfh[NW], wfl[NW];

    auto loadX = [&](int c) {
        int k0 = c * 32;
        #pragma unroll
        for (int i = 0; i < 4; ++i) {
            int idx = t + i * 256;
            int node = idx >> 4, kp = idx & 15;
            long g = node0 + node;
            int k = k0 + 2 * kp;
            bool ok = (g < n_nodes);
            if constexpr (F16IN) {
                const f16* X = (const f16*)Xv;
                xa[i] = (ok && k < KTOT) ? (float)X[g * KTOT + k] : 0.f;
                xb[i] = (ok && k + 1 < KTOT) ? (float)X[g * KTOT + k + 1] : 0.f;
            } else {
                const float* X = (const float*)Xv;
                xa[i] = (ok && k < KTOT) ? X[g * KTOT + k] : 0.f;
                xb[i] = (ok && k + 1 < KTOT) ? X[g * KTOT + k + 1] : 0.f;
            }
        }
    };
    auto loadW = [&](int c) {
        int k0 = c * 32;
        #pragma unroll
        for (int i = 0; i < NW; ++i) {
            int idx = t + i * 256;
            int ch = idx >> 2, q = idx & 3;
            wfh[i] = *(const bfrag8*)&wth[(size_t)ch * KPAD + k0 + q * 8];
            wfl[i] = *(const bfrag8*)&wtl[(size_t)ch * KPAD + k0 + q * 8];
        }
    };
    auto storeLDS = [&]() {
        #pragma unroll
        for (int i = 0; i < 4; ++i) {
            int idx = t + i * 256;
            int node = idx >> 4, kp = idx & 15;
            ushort_t ha = (ushort_t)(__float_as_uint(xa[i]) >> 16);
            ushort_t la = f2bf(xa[i] - bf2f(ha));
            ushort_t hb = (ushort_t)(__float_as_uint(xb[i]) >> 16);
            ushort_t lb = f2bf(xb[i] - bf2f(hb));
            *(unsigned*)&xsh[node][2 * kp] = (unsigned)ha | ((unsigned)hb << 16);
            *(unsigned*)&xsl[node][2 * kp] = (unsigned)la | ((unsigned)lb << 16);
        }
        #pragma unroll
        for (int i = 0; i < NW; ++i) {
            int idx = t + i * 256;
            int ch = idx >> 2, q = idx & 3;
            *(bfrag8*)&wsh[ch][q * 8] = wfh[i];
            *(bfrag8*)&wsl[ch][q * 8] = wfl[i];
        }
    };

    loadX(0); loadW(0);
    for (int c = 0; c < NCHUNK; ++c) {
        storeLDS();
        __syncthreads();
        if (c + 1 < NCHUNK) { loadX(c + 1); loadW(c + 1); }
        bfrag8 ah = *(const bfrag8*)&xsh[arow][kq];
        bfrag8 al = *(const bfrag8*)&xsl[arow][kq];
        #pragma unroll
        for (int ct = 0; ct < NCT; ++ct) {
            bfrag8 bh = *(const bfrag8*)&wsh[ct * 16 + (l & 15)][kq];
            bfrag8 bl = *(const bfrag8*)&wsl[ct * 16 + (l & 15)][kq];
            acc[ct] = __builtin_amdgcn_mfma_f32_16x16x32_bf16(ah, bh, acc[ct], 0, 0, 0);
            acc[ct] = __builtin_amdgcn_mfma_f32_16x16x32_bf16(ah, bl, acc[ct], 0, 0, 0);
            acc[ct] = __builtin_amdgcn_mfma_f32_16x16x32_bf16(al, bh, acc[ct], 0, 0, 0);
        }
        __syncthreads();
    }

    int nl = wid * 16 + (l >> 4) * 4;
    float dv[4];
    #pragma unroll
    for (int j = 0; j < 4; ++j) {
        long node = node0 + nl + j;
        dv[j] = (node < n_nodes) ? dis[node] : 0.f;
    }
    #pragma unroll
    for (int ct = 0; ct < NCT; ++ct) {
        int ch = ct * 16 + (l & 15);
        #pragma unroll
        for (int j = 0; j < 4; ++j) {
            long node = node0 + nl + j;
            if (node < n_nodes)
                M[node * NOUT + ch] = (f16)(acc[ct][j] * dv[j]);
        }
    }
}

// ---------------- aggregation layer 1: 128 ch fp16, wave-per-node ----------------
// 4 edge-groups x 16 lanes, 16B/lane: one dwordx4 load covers 4 edges.
// out (fp16) = relu(dn * (ms[n] + sum ms[src]) + b1)
__global__ void agg1_kernel(const f16* __restrict__ ms, const int* __restrict__ srt,
                            const int* __restrict__ off, const float* __restrict__ dis,
                            const float* __restrict__ b1, f16* __restrict__ h1) {
    int wave = threadIdx.x >> 6;
    int lane = threadIdx.x & 63;
    int n = blockIdx.x * 4 + wave;
    if (n >= N_NODES) return;
    int g = lane >> 4, p = lane & 15;
    float dn = dis[n];
    float acc[8];
    {   // self row: group 0 only
        f16x8 v = *(const f16x8*)(ms + (size_t)n * 128 + p * 8);
        float wm = (g == 0) ? 1.f : 0.f;
        #pragma unroll
        for (int i = 0; i < 8; ++i) acc[i] = wm * (float)v[i];
    }
    int s0 = off[n], s1 = off[n + 1];
    for (int base = s0; base < s1; base += 64) {
        int sv = (base + lane < s1) ? srt[base + lane] : 0;
        int cnt = min(64, s1 - base);
        int j = 0;
        for (; j + 15 < cnt; j += 16) {   // 4 independent loads, 16 edges
            int i0 = __shfl(sv, j + g);
            int i1 = __shfl(sv, j + 4 + g);
            int i2 = __shfl(sv, j + 8 + g);
            int i3 = __shfl(sv, j + 12 + g);
            f16x8 v0 = *(const f16x8*)(ms + (size_t)i0 * 128 + p * 8);
            f16x8 v1 = *(const f16x8*)(ms + (size_t)i1 * 128 + p * 8);
            f16x8 v2 = *(const f16x8*)(ms + (size_t)i2 * 128 + p * 8);
            f16x8 v3 = *(const f16x8*)(ms + (size_t)i3 * 128 + p * 8);
            #pragma unroll
            for (int i = 0; i < 8; ++i)
                acc[i] += (float)v0[i] + (float)v1[i] + (float)v2[i] + (float)v3[i];
        }
        for (; j < cnt; j += 4) {          // masked tail, 4 edges
            int idx = __shfl(sv, j + g);
            float wm = (j + g < cnt) ? 1.f : 0.f;
            f16x8 v = *(const f16x8*)(ms + (size_t)idx * 128 + p * 8);
            #pragma unroll
            for (int i = 0; i < 8; ++i) acc[i] = fmaf(wm, (float)v[i], acc[i]);
        }
    }
    // combine the 4 groups (lanes p, p+16, p+32, p+48)
    #pragma unroll
    for (int i = 0; i < 8; ++i) {
        acc[i] += __shfl_xor(acc[i], 16);
        acc[i] += __shfl_xor(acc[i], 32);
    }
    if (lane < 16) {
        float4 ba = ((const float4*)b1)[lane * 2];
        float4 bb = ((const float4*)b1)[lane * 2 + 1];
        float bv[8] = {ba.x, ba.y, ba.z, ba.w, bb.x, bb.y, bb.z, bb.w};
        f16x8 r;
        #pragma unroll
        for (int i = 0; i < 8; ++i)
            r[i] = (f16)fmaxf(acc[i] * dn + bv[i], 0.f);
        *(f16x8*)(h1 + (size_t)n * 128 + lane * 8) = r;
    }
}

// ---------------- aggregation layer 2 (64 ch fp16) + output GEMM (64 -> 2) ----------------
// 8 edge-groups x 8 lanes, 16B/lane: one dwordx4 load covers 8 edges.
__global__ void agg2_kernel(const f16* __restrict__ ms, const int* __restrict__ srt,
                            const int* __restrict__ off, const float* __restrict__ dis,
                            const float* __restrict__ b2, const float* __restrict__ Wo,
                            const float* __restrict__ bo, float* __restrict__ out) {
    int wave = threadIdx.x >> 6;
    int lane = threadIdx.x & 63;
    int n = blockIdx.x * 4 + wave;
    if (n >= N_NODES) return;
    int g = lane >> 3, p = lane & 7;
    float dn = dis[n];
    float acc[8];
    {   // self row: group 0 only
        f16x8 v = *(const f16x8*)(ms + (size_t)n * 64 + p * 8);
        float wm = (g == 0) ? 1.f : 0.f;
        #pragma unroll
        for (int i = 0; i < 8; ++i) acc[i] = wm * (float)v[i];
    }
    int s0 = off[n], s1 = off[n + 1];
    for (int base = s0; base < s1; base += 64) {
        int sv = (base + lane < s1) ? srt[base + lane] : 0;
        int cnt = min(64, s1 - base);
        int j = 0;
        for (; j + 15 < cnt; j += 16) {   // 2 loads, 16 edges
            int i0 = __shfl(sv, j + g);
            int i1 = __shfl(sv, j + 8 + g);
            f16x8 v0 = *(const f16x8*)(ms + (size_t)i0 * 64 + p * 8);
            f16x8 v1 = *(const f16x8*)(ms + (size_t)i1 * 64 + p * 8);
            #pragma unroll
            for (int i = 0; i < 8; ++i)
                acc[i] += (float)v0[i] + (float)v1[i];
        }
        for (; j < cnt; j += 8) {          // masked tail, 8 edges
            int idx = __shfl(sv, j + g);
            float wm = (j + g < cnt) ? 1.f : 0.f;
            f16x8 v = *(const f16x8*)(ms + (size_t)idx * 64 + p * 8);
            #pragma unroll
            for (int i = 0; i < 8; ++i) acc[i] = fmaf(wm, (float)v[i], acc[i]);
        }
    }
    // combine the 8 groups (lanes p, p+8, ..., p+56)
    #pragma unroll
    for (int i = 0; i < 8; ++i) {
        acc[i] += __shfl_xor(acc[i], 8);
        acc[i] += __shfl_xor(acc[i], 16);
        acc[i] += __shfl_xor(acc[i], 32);
    }
    // fused output GEMM: channels [8p, 8p+8)
    float p0 = 0.f, p1 = 0.f;
    #pragma unroll
    for (int i = 0; i < 8; ++i) {
        int ch = p * 8 + i;
        float hc = fmaxf(acc[i] * dn + b2[ch], 0.f);
        p0 = fmaf(hc, Wo[ch * 2], p0);
        p1 = fmaf(hc, Wo[ch * 2 + 1], p1);
    }
    p0 += __shfl_xor(p0, 1); p1 += __shfl_xor(p1, 1);
    p0 += __shfl_xor(p0, 2); p1 += __shfl_xor(p1, 2);
    p0 += __shfl_xor(p0, 4); p1 += __shfl_xor(p1, 4);
    if (lane == 0) {
        out[(size_t)n * 2]     = p0 + bo[0];
        out[(size_t)n * 2 + 1] = p1 + bo[1];
    }
}

// ---------------- launch ----------------
extern "C" void kernel_launch(void* const* d_in, const int* in_sizes, int n_in,
                              void* d_out, int out_size, void* d_ws, size_t ws_size,
                              hipStream_t stream) {
    const float* x  = (const float*)d_in[0];
    const int*   ei = (const int*)d_in[1];
    const int*   row = ei;
    const int*   col = ei + N_EDGES;
    const float* W1 = (const float*)d_in[2];
    const float* b1 = (const float*)d_in[3];
    const float* W2 = (const float*)d_in[4];
    const float* b2 = (const float*)d_in[5];
    const float* Wo = (const float*)d_in[6];
    const float* bo = (const float*)d_in[7];
    float* out = (float*)d_out;

    char* base = (char*)d_ws;
    auto alloc = [&](size_t bytes) {
        char* p = base;
        base += (bytes + 255) & ~(size_t)255;
        return p;
    };
    int*      cnt  = (int*)alloc((size_t)N_NODES * 4);
    int*      off  = (int*)alloc((size_t)(N_NODES + 1) * 4);
    float*    dis  = (float*)alloc((size_t)N_NODES * 4);
    int*      bsum = (int*)alloc(256);
    int*      bfill= (int*)alloc((size_t)NBUCK * 4);
    unsigned* tmp  = (unsigned*)alloc((size_t)NBUCK * BCAP * 4 + 4096);
    int*      srt  = (int*)alloc((size_t)N_EDGES * 4);
    f16*      m    = (f16*)alloc((size_t)N_NODES * 128 * 2);   // m1, reused as m2
    f16*      h1   = (f16*)alloc((size_t)N_NODES * 128 * 2);
    ushort_t* wt1h = (ushort_t*)alloc((size_t)128 * 192 * 2);
    ushort_t* wt1l = (ushort_t*)alloc((size_t)128 * 192 * 2);
    ushort_t* wt2h = (ushort_t*)alloc((size_t)64 * 128 * 2);
    ushort_t* wt2l = (ushort_t*)alloc((size_t)64 * 128 * 2);

    hipMemsetAsync(bfill, 0, (size_t)NBUCK * 4, stream);
    bucketA_kernel<<<PA_BLOCKS, 256, 0, stream>>>(row, col, bfill, tmp);
    countB_kernel<<<NBUCK, 256, 0, stream>>>(tmp, bfill, cnt, dis);
    scan1_kernel<<<NB_SCAN, 256, 0, stream>>>(cnt, off, bsum, N_NODES);
    scan2_kernel<<<1, 64, 0, stream>>>(bsum, NB_SCAN);
    scan3_kernel<<<(N_NODES + 256) / 256, 256, 0, stream>>>(off, bsum, N_NODES, N_EDGES);
    bucketB_kernel<<<NBUCK, 256, 0, stream>>>(tmp, bfill, off, srt);
    wsplit_kernel<<<(128 * 192 + 64 * 128 + 255) / 256, 256, 0, stream>>>(W1, W2, wt1h, wt1l, wt2h, wt2l);

    // layer 1: m = dis * (x @ W1)  [MFMA split-bf16 -> fp16]
    mfma_gemm_kernel<128, 165, 192, false><<<(N_NODES + 63) / 64, 256, 0, stream>>>(x, wt1h, wt1l, dis, m, N_NODES);
    agg1_kernel<<<(N_NODES + 3) / 4, 256, 0, stream>>>(m, srt, off, dis, b1, h1);

    // layer 2: m = dis * (h1 @ W2)  [MFMA split-bf16 -> fp16, fp16 input]
    mfma_gemm_kernel<64, 128, 128, true><<<(N_NODES + 63) / 64, 256, 0, stream>>>(h1, wt2h, wt2l, dis, m, N_NODES);
    agg2_kernel<<<(N_NODES + 3) / 4, 256, 0, stream>>>(m, srt, off, dis, b2, Wo, bo, out);
}